// Round 2
// baseline (658.369 us; speedup 1.0000x reference)
//
#include <hip/hip_runtime.h>
#include <hip/hip_bf16.h>

// Swin block, MI355X. v2: N-looped GEMMs (A read once), LN1/LN2/proj fused.
// B=32 H=W=64 C=192 WS=8 SS=4 NH=6 Dh=32 N=64 nW=64; T = 131072 tokens.

#define DI __device__ __forceinline__

typedef __attribute__((ext_vector_type(8))) short bhalf8;   // 8 bf16 (4 VGPR)
typedef __attribute__((ext_vector_type(4))) float f32x4;
typedef unsigned short u16;
typedef unsigned int   u32;

DI u16 f2bf(float f){                       // RNE f32->bf16
  union { float f; u32 u; } v; v.f = f;
  u32 r = v.u + 0x7FFFu + ((v.u >> 16) & 1u);
  return (u16)(r >> 16);
}
DI u32 f2bf2(float a, float b){ return (u32)f2bf(a) | ((u32)f2bf(b) << 16); }

static const int T_TOK = 131072;

// window-token index t -> global token g (shift+partition map; same for gather & scatter)
DI int tok2glob(int t){
  int n = t & 63, widx = t >> 6;
  int b = widx >> 6, wi = widx & 63;
  int hh = ((wi >> 3) << 3) + (n >> 3);
  int ww = ((wi & 7) << 3) + (n & 7);
  int hs = (hh + 4) & 63, wsv = (ww + 4) & 63;
  return (b << 12) + (hs << 6) + wsv;
}

// ------------- weight prep: W(K,N) fp32 -> Wt(N,K) bf16 -------------
__global__ void transcast_kernel(const float* __restrict__ W, u16* __restrict__ Wt, int K, int N){
  int idx = blockIdx.x * 256 + threadIdx.x;
  if (idx < K*N){
    int n = idx / K, k = idx - n*K;
    Wt[idx] = f2bf(W[(size_t)k * N + n]);
  }
}

// ---------------- fused LN + GEMM, K=192, M-tile 128, N-loop ----------------
// out[M x NT*64] (bf16) = act( LN(X[gather]) @ Wt^T + bias ),  act = id or gelu
template<int PERM, int GELU>
__global__ __launch_bounds__(256) void gemm_ln_kernel(
    const float* __restrict__ X, const float* __restrict__ gam, const float* __restrict__ bet,
    const u16* __restrict__ Bt, const float* __restrict__ bias,
    u16* __restrict__ outH, int NT){
  __shared__ u16 As[128*192];
  __shared__ u16 Bs[64*192];
  int tid = threadIdx.x;
  int mBase = blockIdx.x << 7;

  // LN staging: 2 batches of 64 rows, 4 threads per row (48 f32 each)
  int qrow = tid >> 2, quarter = tid & 3;
  #pragma unroll
  for (int batch = 0; batch < 2; batch++){
    int row = batch*64 + qrow;
    int t = mBase + row;
    int g = PERM ? tok2glob(t) : t;
    const float4* xr = (const float4*)(X + (size_t)g*192 + quarter*48);
    float4 va[12];
    float s = 0.f, sq = 0.f;
    #pragma unroll
    for (int j = 0; j < 12; j++){
      va[j] = xr[j];
      s  += va[j].x + va[j].y + va[j].z + va[j].w;
      sq += va[j].x*va[j].x + va[j].y*va[j].y + va[j].z*va[j].z + va[j].w*va[j].w;
    }
    s  += __shfl_xor(s, 1, 64);  sq += __shfl_xor(sq, 1, 64);
    s  += __shfl_xor(s, 2, 64);  sq += __shfl_xor(sq, 2, 64);
    float mean = s * (1.f/192.f);
    float rstd = rsqrtf(sq * (1.f/192.f) - mean*mean + 1e-5f);
    const float4* g4 = (const float4*)(gam + quarter*48);
    const float4* b4 = (const float4*)(bet + quarter*48);
    #pragma unroll
    for (int j2 = 0; j2 < 6; j2++){
      float4 v0 = va[2*j2], v1 = va[2*j2+1];
      float4 g0 = g4[2*j2], g1 = g4[2*j2+1];
      float4 b0 = b4[2*j2], b1 = b4[2*j2+1];
      uint4 pk;
      pk.x = f2bf2((v0.x-mean)*rstd*g0.x+b0.x, (v0.y-mean)*rstd*g0.y+b0.y);
      pk.y = f2bf2((v0.z-mean)*rstd*g0.z+b0.z, (v0.w-mean)*rstd*g0.w+b0.w);
      pk.z = f2bf2((v1.x-mean)*rstd*g1.x+b1.x, (v1.y-mean)*rstd*g1.y+b1.y);
      pk.w = f2bf2((v1.z-mean)*rstd*g1.z+b1.z, (v1.w-mean)*rstd*g1.w+b1.w);
      int gk = quarter*6 + j2;                       // 24 granules/row
      *(uint4*)&As[row*192 + ((gk ^ (row & 7)) << 3)] = pk;
    }
  }
  __syncthreads();

  int lane = tid & 63, w = tid >> 6;
  int wr = w >> 1, wc = w & 1, lr = lane & 15, lg = lane >> 4;
  // hoist all A fragments (full K=192) into registers
  bhalf8 aF[6][4];
  #pragma unroll
  for (int kk = 0; kk < 6; kk++)
    #pragma unroll
    for (int i = 0; i < 4; i++){
      int row = wr*64 + i*16 + lr;
      int gk = (kk*4 + lg) ^ (row & 7);
      aF[kk][i] = *(const bhalf8*)&As[row*192 + gk*8];
    }

  int ldo = NT << 6;
  for (int nt = 0; nt < NT; nt++){
    __syncthreads();                                 // prev tile's Bs reads done
    #pragma unroll
    for (int t6 = 0; t6 < 6; t6++){                  // stage Bs: 64 rows x 24 granules
      int gi = t6*256 + tid;
      int brow = gi / 24, gk = gi - brow*24;
      uint4 v = *(const uint4*)&Bt[(size_t)(nt*64 + brow)*192 + gk*8];
      *(uint4*)&Bs[brow*192 + ((gk ^ (brow & 7)) << 3)] = v;
    }
    __syncthreads();
    f32x4 acc[4][2];
    #pragma unroll
    for (int i=0;i<4;i++)
      #pragma unroll
      for (int n=0;n<2;n++) acc[i][n] = (f32x4){0.f,0.f,0.f,0.f};
    #pragma unroll
    for (int kk = 0; kk < 6; kk++){
      bhalf8 bF[2];
      #pragma unroll
      for (int n=0;n<2;n++){
        int col = wc*32 + n*16 + lr;
        int gk = (kk*4 + lg) ^ (col & 7);
        bF[n] = *(const bhalf8*)&Bs[col*192 + gk*8];
      }
      #pragma unroll
      for (int i=0;i<4;i++)
        #pragma unroll
        for (int n=0;n<2;n++)
          acc[i][n] = __builtin_amdgcn_mfma_f32_16x16x32_bf16(aF[kk][i], bF[n], acc[i][n], 0, 0, 0);
    }
    #pragma unroll
    for (int i=0;i<4;i++){
      #pragma unroll
      for (int n=0;n<2;n++){
        int col = (nt<<6) + wc*32 + n*16 + lr;
        float bv = bias[col];
        #pragma unroll
        for (int r=0;r<4;r++){
          int row = mBase + wr*64 + i*16 + lg*4 + r;
          float v = acc[i][n][r] + bv;
          if (GELU) v = 0.5f * v * (1.0f + erff(v * 0.70710678118654752f));
          outH[(size_t)row * ldo + col] = f2bf(v);
        }
      }
    }
  }
}

// ---------------- fc2: C(M,192) = A(M,768) @ Wt(192,768)^T, all N resident ----------------
__global__ __launch_bounds__(256) void fc2_kernel(const u16* __restrict__ A,
    const u16* __restrict__ Bt, const float* __restrict__ bias, float* __restrict__ out){
  __shared__ u16 As[128*64];
  __shared__ u16 Bs[192*64];
  int tid = threadIdx.x, mBase = blockIdx.x << 7;
  int lane = tid & 63, w = tid >> 6;
  int wr = w >> 1, wc = w & 1, lr = lane & 15, lg = lane >> 4;
  f32x4 acc[3][4][2];
  #pragma unroll
  for (int nt=0;nt<3;nt++)
    #pragma unroll
    for (int i=0;i<4;i++)
      #pragma unroll
      for (int n=0;n<2;n++) acc[nt][i][n] = (f32x4){0.f,0.f,0.f,0.f};

  int r0 = tid >> 3, ko = (tid & 7) << 3;
  for (int kb = 0; kb < 12; kb++){
    int kOff = kb << 6;
    if (kb) __syncthreads();
    #pragma unroll
    for (int it=0; it<4; it++){                     // A tile 128x64
      int row = r0 + it*32;
      uint4 v = *(const uint4*)&A[(size_t)(mBase + row)*768 + kOff + ko];
      *(uint4*)&As[row*64 + ((((ko>>3) ^ (row&7))) << 3)] = v;
    }
    #pragma unroll
    for (int it=0; it<6; it++){                     // B tile 192x64
      int brow = r0 + it*32;
      uint4 v = *(const uint4*)&Bt[(size_t)brow*768 + kOff + ko];
      *(uint4*)&Bs[brow*64 + ((((ko>>3) ^ (brow&7))) << 3)] = v;
    }
    __syncthreads();
    #pragma unroll
    for (int kk=0; kk<2; kk++){
      bhalf8 af[4], bf[3][2];
      #pragma unroll
      for (int i=0;i<4;i++){
        int row = wr*64 + i*16 + lr;
        af[i] = *(const bhalf8*)&As[row*64 + (((kk*4+lg) ^ (row&7)) << 3)];
      }
      #pragma unroll
      for (int nt=0;nt<3;nt++)
        #pragma unroll
        for (int n=0;n<2;n++){
          int col = nt*64 + wc*32 + n*16 + lr;
          bf[nt][n] = *(const bhalf8*)&Bs[col*64 + (((kk*4+lg) ^ (col&7)) << 3)];
        }
      #pragma unroll
      for (int nt=0;nt<3;nt++)
        #pragma unroll
        for (int i=0;i<4;i++)
          #pragma unroll
          for (int n=0;n<2;n++)
            acc[nt][i][n] = __builtin_amdgcn_mfma_f32_16x16x32_bf16(af[i], bf[nt][n], acc[nt][i][n], 0, 0, 0);
    }
  }
  #pragma unroll
  for (int nt=0;nt<3;nt++)
    #pragma unroll
    for (int i=0;i<4;i++)
      #pragma unroll
      for (int n=0;n<2;n++){
        int col = nt*64 + wc*32 + n*16 + lr;
        float bv = bias[col];
        #pragma unroll
        for (int r=0;r<4;r++){
          int row = mBase + wr*64 + i*16 + lg*4 + r;
          size_t o = (size_t)row*192 + col;
          out[o] = out[o] + bv + acc[nt][i][n][r];
        }
      }
}

// ---------------- windowed attention + proj + residual: 1 block/window ----------------
DI int region_id(int hpos, int wpos){
  int rh = (hpos < 56) ? 0 : ((hpos < 60) ? 1 : 2);
  int rw = (wpos < 56) ? 0 : ((wpos < 60) ? 1 : 2);
  return rh*3 + rw;
}

__global__ __launch_bounds__(384) void attn_proj_kernel(const u16* __restrict__ QKV,
    const u16* __restrict__ projWt, const float* __restrict__ proj_b,
    const float* __restrict__ x, float* __restrict__ out, const float* __restrict__ rpb){
  __shared__ u16 Plds[6*64*64];   // P (per head), later aliased as Clds[64][192]
  __shared__ u16 Vt[6][32*64];    // V^T, XOR-swizzled
  __shared__ float Rlds[225*6];
  int widx = blockIdx.x;
  int h = threadIdx.x >> 6, lane = threadIdx.x & 63;
  int lr = lane & 15, lg = lane >> 4;

  for (int i = threadIdx.x; i < 225*6; i += 384) Rlds[i] = rpb[i];

  { // stage V transposed: lane = token
    const uint4* vp4 = (const uint4*)(QKV + (size_t)(widx*64 + lane)*576 + 384 + h*32);
    #pragma unroll
    for (int q4 = 0; q4 < 4; q4++){
      union { uint4 v; u16 s[8]; } u; u.v = vp4[q4];
      #pragma unroll
      for (int j = 0; j < 8; j++){
        int d = q4*8 + j;
        Vt[h][d*64 + (lane ^ ((d & 7) << 3))] = u.s[j];
      }
    }
  }

  bhalf8 qf[4], kf[4];
  #pragma unroll
  for (int i=0;i<4;i++){
    int row = i*16 + lr;
    qf[i] = *(const bhalf8*)(QKV + (size_t)(widx*64 + row)*576 + h*32 + (lg<<3));
  }
  #pragma unroll
  for (int j=0;j<4;j++){
    int col = j*16 + lr;
    kf[j] = *(const bhalf8*)(QKV + (size_t)(widx*64 + col)*576 + 192 + h*32 + (lg<<3));
  }
  f32x4 sc[4][4];
  f32x4 zero = (f32x4){0.f,0.f,0.f,0.f};
  #pragma unroll
  for (int i=0;i<4;i++)
    #pragma unroll
    for (int j=0;j<4;j++)
      sc[i][j] = __builtin_amdgcn_mfma_f32_16x16x32_bf16(qf[i], kf[j], zero, 0, 0, 0);

  __syncthreads();   // Rlds ready

  int mwin = widx >> 5;                 // faithful to reference reshape quirk
  int mh0 = (mwin >> 3) << 3, mw0 = (mwin & 7) << 3;
  #pragma unroll
  for (int i=0;i<4;i++){
    #pragma unroll
    for (int r=0;r<4;r++){
      int row = i*16 + lg*4 + r;
      int ih = row >> 3, iw = row & 7;
      int ridr = region_id(mh0 + ih, mw0 + iw);
      float vals[4];
      #pragma unroll
      for (int j=0;j<4;j++){
        int col = j*16 + lr;
        int jh = col >> 3, jw = col & 7;
        float bias = Rlds[((ih-jh+7)*15 + (iw-jw+7))*6 + h];
        int ridc = region_id(mh0 + jh, mw0 + jw);
        vals[j] = sc[i][j][r] * 0.17677669529663687f + bias + ((ridr==ridc) ? 0.f : -100.f);
      }
      float mx = fmaxf(fmaxf(vals[0],vals[1]), fmaxf(vals[2],vals[3]));
      #pragma unroll
      for (int d=1; d<16; d<<=1) mx = fmaxf(mx, __shfl_xor(mx, d, 64));
      float sum = 0.f;
      #pragma unroll
      for (int j=0;j<4;j++){ vals[j] = expf(vals[j]-mx); sum += vals[j]; }
      #pragma unroll
      for (int d=1; d<16; d<<=1) sum += __shfl_xor(sum, d, 64);
      float inv = 1.f / sum;
      #pragma unroll
      for (int j=0;j<4;j++){
        int col = j*16 + lr;
        Plds[h*4096 + row*64 + (col ^ ((row & 7) << 3))] = f2bf(vals[j]*inv);
      }
    }
  }

  // PV (each wave reads only its own Plds[h]/Vt[h] regions; within-wave ordering)
  f32x4 oa[4][2];
  #pragma unroll
  for (int i=0;i<4;i++)
    #pragma unroll
    for (int n=0;n<2;n++) oa[i][n] = zero;
  #pragma unroll
  for (int kb=0; kb<2; kb++){
    bhalf8 pf[4], vf[2];
    int k = (kb<<5) + (lg<<3);
    #pragma unroll
    for (int i=0;i<4;i++){
      int row = i*16 + lr;
      pf[i] = *(const bhalf8*)&Plds[h*4096 + row*64 + (k ^ ((row&7)<<3))];
    }
    #pragma unroll
    for (int n=0;n<2;n++){
      int d = n*16 + lr;
      vf[n] = *(const bhalf8*)&Vt[h][d*64 + (k ^ ((d&7)<<3))];
    }
    #pragma unroll
    for (int i=0;i<4;i++)
      #pragma unroll
      for (int n=0;n<2;n++)
        oa[i][n] = __builtin_amdgcn_mfma_f32_16x16x32_bf16(pf[i], vf[n], oa[i][n], 0, 0, 0);
  }

  // ---- fused proj: ctx -> Clds (aliases Plds), then 64x192 @ 192x192 ----
  __syncthreads();                       // all PV reads of Plds done
  u16* Clds = &Plds[0];                  // [64][192], granule-swizzled
  #pragma unroll
  for (int i=0;i<4;i++)
    #pragma unroll
    for (int n=0;n<2;n++)
      #pragma unroll
      for (int r=0;r<4;r++){
        int row = i*16 + lg*4 + r;
        int col = h*32 + n*16 + lr;
        Clds[row*192 + (((col>>3) ^ (row&7)) << 3) + (col & 7)] = f2bf(oa[i][n][r]);
      }
  __syncthreads();                       // ctx complete

  f32x4 pacc[4][2];
  #pragma unroll
  for (int i=0;i<4;i++)
    #pragma unroll
    for (int n=0;n<2;n++) pacc[i][n] = zero;
  #pragma unroll
  for (int kk=0; kk<6; kk++){
    bhalf8 af[4], bf[2];
    #pragma unroll
    for (int i=0;i<4;i++){
      int row = i*16 + lr;
      int gk = (kk*4 + lg) ^ (row & 7);
      af[i] = *(const bhalf8*)&Clds[row*192 + gk*8];
    }
    #pragma unroll
    for (int n=0;n<2;n++){
      int col = h*32 + n*16 + lr;
      bf[n] = *(const bhalf8*)&projWt[(size_t)col*192 + kk*32 + (lg<<3)];
    }
    #pragma unroll
    for (int i=0;i<4;i++)
      #pragma unroll
      for (int n=0;n<2;n++)
        pacc[i][n] = __builtin_amdgcn_mfma_f32_16x16x32_bf16(af[i], bf[n], pacc[i][n], 0, 0, 0);
  }
  #pragma unroll
  for (int i=0;i<4;i++)
    #pragma unroll
    for (int n=0;n<2;n++){
      int col = h*32 + n*16 + lr;
      float bv = proj_b[col];
      #pragma unroll
      for (int r=0;r<4;r++){
        int rowl = i*16 + lg*4 + r;
        int g = tok2glob(widx*64 + rowl);
        size_t o = (size_t)g*192 + col;
        out[o] = x[o] + bv + pacc[i][n][r];
      }
    }
}

extern "C" void kernel_launch(void* const* d_in, const int* in_sizes, int n_in,
                              void* d_out, int out_size, void* d_ws, size_t ws_size,
                              hipStream_t stream){
  const float* x      = (const float*)d_in[0];
  const float* n1g    = (const float*)d_in[1];
  const float* n1b    = (const float*)d_in[2];
  const float* qkv_w  = (const float*)d_in[3];
  const float* qkv_b  = (const float*)d_in[4];
  const float* proj_w = (const float*)d_in[5];
  const float* proj_b = (const float*)d_in[6];
  const float* rpb    = (const float*)d_in[7];
  const float* n2g    = (const float*)d_in[8];
  const float* n2b    = (const float*)d_in[9];
  const float* fc1_w  = (const float*)d_in[10];
  const float* fc1_b  = (const float*)d_in[11];
  const float* fc2_w  = (const float*)d_in[12];
  const float* fc2_b  = (const float*)d_in[13];
  float* out = (float*)d_out;

  const size_t T = (size_t)T_TOK;
  u16* QKV  = (u16*)d_ws;            // T*576; H1 (T*768) aliases same region
  u16* H1   = QKV;                   // reused after attn consumes QKV
  u16* WT   = QKV + T*768;
  u16* qkvWt  = WT;
  u16* projWt = qkvWt + 576*192;
  u16* fc1Wt  = projWt + 192*192;
  u16* fc2Wt  = fc1Wt + 768*192;

  transcast_kernel<<<dim3((192*576+255)/256),256,0,stream>>>(qkv_w, qkvWt, 192, 576);
  transcast_kernel<<<dim3((192*192+255)/256),256,0,stream>>>(proj_w, projWt, 192, 192);
  transcast_kernel<<<dim3((192*768+255)/256),256,0,stream>>>(fc1_w, fc1Wt, 192, 768);
  transcast_kernel<<<dim3((768*192+255)/256),256,0,stream>>>(fc2_w, fc2Wt, 768, 192);

  // LN1 + qkv GEMM (gathered rows), N=576
  gemm_ln_kernel<1,0><<<dim3(1024),256,0,stream>>>(x, n1g, n1b, qkvWt, qkv_b, QKV, 9);
  // attention + proj + residual -> out (xmid)
  attn_proj_kernel<<<dim3(2048),384,0,stream>>>(QKV, projWt, proj_b, x, out, rpb);
  // LN2 + fc1 GEMM + gelu, N=768
  gemm_ln_kernel<0,1><<<dim3(1024),256,0,stream>>>(out, n2g, n2b, fc1Wt, fc1_b, H1, 12);
  // fc2 + residual (in-place on out)
  fc2_kernel<<<dim3(1024),256,0,stream>>>(H1, fc2Wt, fc2_b, out);
}

// Round 3
// 634.836 us; speedup vs baseline: 1.0371x; 1.0371x over previous
//
#include <hip/hip_runtime.h>
#include <hip/hip_bf16.h>

// Swin block, MI355X. v3: A-resident N-loop GEMMs with B-frags direct from L2
// (no Bs staging, no main-loop barriers), fc2 double-buffered. LN1/LN2/proj fused.
// B=32 H=W=64 C=192 WS=8 SS=4 NH=6 Dh=32 N=64 nW=64; T = 131072 tokens.

#define DI __device__ __forceinline__

typedef __attribute__((ext_vector_type(8))) short bhalf8;   // 8 bf16 (4 VGPR)
typedef __attribute__((ext_vector_type(4))) float f32x4;
typedef unsigned short u16;
typedef unsigned int   u32;

DI u16 f2bf(float f){                       // RNE f32->bf16
  union { float f; u32 u; } v; v.f = f;
  u32 r = v.u + 0x7FFFu + ((v.u >> 16) & 1u);
  return (u16)(r >> 16);
}
DI u32 f2bf2(float a, float b){ return (u32)f2bf(a) | ((u32)f2bf(b) << 16); }

static const int T_TOK = 131072;

// window-token index t -> global token g (shift+partition map; same for gather & scatter)
DI int tok2glob(int t){
  int n = t & 63, widx = t >> 6;
  int b = widx >> 6, wi = widx & 63;
  int hh = ((wi >> 3) << 3) + (n >> 3);
  int ww = ((wi & 7) << 3) + (n & 7);
  int hs = (hh + 4) & 63, wsv = (ww + 4) & 63;
  return (b << 12) + (hs << 6) + wsv;
}

// ------------- weight prep: W(K,N) fp32 -> Wt(N,K) bf16 -------------
__global__ void transcast_kernel(const float* __restrict__ W, u16* __restrict__ Wt, int K, int N){
  int idx = blockIdx.x * 256 + threadIdx.x;
  if (idx < K*N){
    int n = idx / K, k = idx - n*K;
    Wt[idx] = f2bf(W[(size_t)k * N + n]);
  }
}

// ---------------- fused LN + GEMM, K=192, M-tile 128, N-loop, B from L2 ----------------
// out[M x NT*64] (bf16) = act( LN(X[gather]) @ Wt^T + bias ),  act = id or gelu
template<int PERM, int GELU>
__global__ __launch_bounds__(256) void gemm_ln_kernel(
    const float* __restrict__ X, const float* __restrict__ gam, const float* __restrict__ bet,
    const u16* __restrict__ Bt, const float* __restrict__ bias,
    u16* __restrict__ outH, int NT){
  __shared__ u16 As[128*192];
  int tid = threadIdx.x;
  int mBase = blockIdx.x << 7;

  // LN staging: 2 batches of 64 rows, 4 threads per row (48 f32 each)
  int qrow = tid >> 2, quarter = tid & 3;
  #pragma unroll
  for (int batch = 0; batch < 2; batch++){
    int row = batch*64 + qrow;
    int t = mBase + row;
    int g = PERM ? tok2glob(t) : t;
    const float4* xr = (const float4*)(X + (size_t)g*192 + quarter*48);
    float4 va[12];
    float s = 0.f, sq = 0.f;
    #pragma unroll
    for (int j = 0; j < 12; j++){
      va[j] = xr[j];
      s  += va[j].x + va[j].y + va[j].z + va[j].w;
      sq += va[j].x*va[j].x + va[j].y*va[j].y + va[j].z*va[j].z + va[j].w*va[j].w;
    }
    s  += __shfl_xor(s, 1, 64);  sq += __shfl_xor(sq, 1, 64);
    s  += __shfl_xor(s, 2, 64);  sq += __shfl_xor(sq, 2, 64);
    float mean = s * (1.f/192.f);
    float rstd = rsqrtf(sq * (1.f/192.f) - mean*mean + 1e-5f);
    const float4* g4 = (const float4*)(gam + quarter*48);
    const float4* b4 = (const float4*)(bet + quarter*48);
    #pragma unroll
    for (int j2 = 0; j2 < 6; j2++){
      float4 v0 = va[2*j2], v1 = va[2*j2+1];
      float4 g0 = g4[2*j2], g1 = g4[2*j2+1];
      float4 b0 = b4[2*j2], b1 = b4[2*j2+1];
      uint4 pk;
      pk.x = f2bf2((v0.x-mean)*rstd*g0.x+b0.x, (v0.y-mean)*rstd*g0.y+b0.y);
      pk.y = f2bf2((v0.z-mean)*rstd*g0.z+b0.z, (v0.w-mean)*rstd*g0.w+b0.w);
      pk.z = f2bf2((v1.x-mean)*rstd*g1.x+b1.x, (v1.y-mean)*rstd*g1.y+b1.y);
      pk.w = f2bf2((v1.z-mean)*rstd*g1.z+b1.z, (v1.w-mean)*rstd*g1.w+b1.w);
      int gk = quarter*6 + j2;                       // 24 granules/row
      *(uint4*)&As[row*192 + ((gk ^ (row & 7)) << 3)] = pk;
    }
  }
  __syncthreads();

  int lane = tid & 63, w = tid >> 6;
  int wr = w >> 1, wc = w & 1, lr = lane & 15, lg = lane >> 4;
  int ldo = NT << 6;

  for (int nt = 0; nt < NT; nt++){
    // prefetch all 12 B fragments for this N-tile straight from global (L2-hot)
    bhalf8 bF[6][2];
    #pragma unroll
    for (int kk = 0; kk < 6; kk++)
      #pragma unroll
      for (int n = 0; n < 2; n++){
        int col = (nt<<6) + wc*32 + n*16 + lr;
        bF[kk][n] = *(const bhalf8*)&Bt[(size_t)col*192 + kk*32 + (lg<<3)];
      }
    f32x4 acc[4][2];
    #pragma unroll
    for (int i=0;i<4;i++)
      #pragma unroll
      for (int n=0;n<2;n++) acc[i][n] = (f32x4){0.f,0.f,0.f,0.f};
    #pragma unroll
    for (int kk = 0; kk < 6; kk++){
      bhalf8 aF[4];
      #pragma unroll
      for (int i=0;i<4;i++){
        int row = wr*64 + i*16 + lr;
        aF[i] = *(const bhalf8*)&As[row*192 + (((kk*4 + lg) ^ (row & 7)) << 3)];
      }
      #pragma unroll
      for (int i=0;i<4;i++)
        #pragma unroll
        for (int n=0;n<2;n++)
          acc[i][n] = __builtin_amdgcn_mfma_f32_16x16x32_bf16(aF[i], bF[kk][n], acc[i][n], 0, 0, 0);
    }
    #pragma unroll
    for (int i=0;i<4;i++){
      #pragma unroll
      for (int n=0;n<2;n++){
        int col = (nt<<6) + wc*32 + n*16 + lr;
        float bv = bias[col];
        #pragma unroll
        for (int r=0;r<4;r++){
          int row = mBase + wr*64 + i*16 + lg*4 + r;
          float v = acc[i][n][r] + bv;
          if (GELU) v = 0.5f * v * (1.0f + erff(v * 0.70710678118654752f));
          outH[(size_t)row * ldo + col] = f2bf(v);
        }
      }
    }
  }
}

// ---------------- fc2: C(M,192) = A(M,768) @ Wt(192,768)^T + residual ----------------
// 512 threads, wave grid 2M x 4N (each wave 64x48), A double-buffered, B from L2.
__global__ __launch_bounds__(512) void fc2_kernel(const u16* __restrict__ A,
    const u16* __restrict__ Bt, const float* __restrict__ bias, float* __restrict__ out){
  __shared__ u16 As[2][128*64];
  int tid = threadIdx.x, mBase = blockIdx.x << 7;
  int lane = tid & 63, w = tid >> 6;
  int wm = w >> 2, wn = w & 3, lr = lane & 15, lg = lane >> 4;
  int r0 = tid >> 3, ko = (tid & 7) << 3;
  f32x4 acc[4][3];
  #pragma unroll
  for (int i=0;i<4;i++)
    #pragma unroll
    for (int n=0;n<3;n++) acc[i][n] = (f32x4){0.f,0.f,0.f,0.f};

  // stage kb=0
  #pragma unroll
  for (int it=0; it<2; it++){
    int row = r0 + it*64;
    uint4 v = *(const uint4*)&A[(size_t)(mBase + row)*768 + ko];
    *(uint4*)&As[0][row*64 + ((((ko>>3) ^ (row&7))) << 3)] = v;
  }

  for (int kb = 0; kb < 12; kb++){
    __syncthreads();
    int cur = kb & 1, nxt = cur ^ 1;
    if (kb < 11){
      #pragma unroll
      for (int it=0; it<2; it++){
        int row = r0 + it*64;
        uint4 v = *(const uint4*)&A[(size_t)(mBase + row)*768 + (kb+1)*64 + ko];
        *(uint4*)&As[nxt][row*64 + ((((ko>>3) ^ (row&7))) << 3)] = v;
      }
    }
    bhalf8 bF[2][3];
    #pragma unroll
    for (int kk=0; kk<2; kk++)
      #pragma unroll
      for (int n=0; n<3; n++){
        int col = wn*48 + n*16 + lr;
        bF[kk][n] = *(const bhalf8*)&Bt[(size_t)col*768 + kb*64 + kk*32 + (lg<<3)];
      }
    #pragma unroll
    for (int kk=0; kk<2; kk++){
      bhalf8 aF[4];
      #pragma unroll
      for (int i=0;i<4;i++){
        int row = wm*64 + i*16 + lr;
        aF[i] = *(const bhalf8*)&As[cur][row*64 + (((kk*4 + lg) ^ (row&7)) << 3)];
      }
      #pragma unroll
      for (int i=0;i<4;i++)
        #pragma unroll
        for (int n=0;n<3;n++)
          acc[i][n] = __builtin_amdgcn_mfma_f32_16x16x32_bf16(aF[i], bF[kk][n], acc[i][n], 0, 0, 0);
    }
  }
  #pragma unroll
  for (int i=0;i<4;i++)
    #pragma unroll
    for (int n=0;n<3;n++){
      int col = wn*48 + n*16 + lr;
      float bv = bias[col];
      #pragma unroll
      for (int r=0;r<4;r++){
        int row = mBase + wm*64 + i*16 + lg*4 + r;
        size_t o = (size_t)row*192 + col;
        out[o] = out[o] + bv + acc[i][n][r];
      }
    }
}

// ---------------- windowed attention + proj + residual: 1 block/window ----------------
DI int region_id(int hpos, int wpos){
  int rh = (hpos < 56) ? 0 : ((hpos < 60) ? 1 : 2);
  int rw = (wpos < 56) ? 0 : ((wpos < 60) ? 1 : 2);
  return rh*3 + rw;
}

__global__ __launch_bounds__(384) void attn_proj_kernel(const u16* __restrict__ QKV,
    const u16* __restrict__ projWt, const float* __restrict__ proj_b,
    const float* __restrict__ x, float* __restrict__ out, const float* __restrict__ rpb){
  __shared__ u16 Plds[6*64*64];   // P (per head), later aliased as Clds[64][192]
  __shared__ u16 Vt[6][32*64];    // V^T, XOR-swizzled
  __shared__ float Rlds[225*6];
  int widx = blockIdx.x;
  int h = threadIdx.x >> 6, lane = threadIdx.x & 63;
  int lr = lane & 15, lg = lane >> 4;

  for (int i = threadIdx.x; i < 225*6; i += 384) Rlds[i] = rpb[i];

  { // stage V transposed: lane = token
    const uint4* vp4 = (const uint4*)(QKV + (size_t)(widx*64 + lane)*576 + 384 + h*32);
    #pragma unroll
    for (int q4 = 0; q4 < 4; q4++){
      union { uint4 v; u16 s[8]; } u; u.v = vp4[q4];
      #pragma unroll
      for (int j = 0; j < 8; j++){
        int d = q4*8 + j;
        Vt[h][d*64 + (lane ^ ((d & 7) << 3))] = u.s[j];
      }
    }
  }

  bhalf8 qf[4], kf[4];
  #pragma unroll
  for (int i=0;i<4;i++){
    int row = i*16 + lr;
    qf[i] = *(const bhalf8*)(QKV + (size_t)(widx*64 + row)*576 + h*32 + (lg<<3));
  }
  #pragma unroll
  for (int j=0;j<4;j++){
    int col = j*16 + lr;
    kf[j] = *(const bhalf8*)(QKV + (size_t)(widx*64 + col)*576 + 192 + h*32 + (lg<<3));
  }
  f32x4 sc[4][4];
  f32x4 zero = (f32x4){0.f,0.f,0.f,0.f};
  #pragma unroll
  for (int i=0;i<4;i++)
    #pragma unroll
    for (int j=0;j<4;j++)
      sc[i][j] = __builtin_amdgcn_mfma_f32_16x16x32_bf16(qf[i], kf[j], zero, 0, 0, 0);

  __syncthreads();   // Rlds ready

  int mwin = widx >> 5;                 // faithful to reference reshape quirk
  int mh0 = (mwin >> 3) << 3, mw0 = (mwin & 7) << 3;
  #pragma unroll
  for (int i=0;i<4;i++){
    #pragma unroll
    for (int r=0;r<4;r++){
      int row = i*16 + lg*4 + r;
      int ih = row >> 3, iw = row & 7;
      int ridr = region_id(mh0 + ih, mw0 + iw);
      float vals[4];
      #pragma unroll
      for (int j=0;j<4;j++){
        int col = j*16 + lr;
        int jh = col >> 3, jw = col & 7;
        float bias = Rlds[((ih-jh+7)*15 + (iw-jw+7))*6 + h];
        int ridc = region_id(mh0 + jh, mw0 + jw);
        vals[j] = sc[i][j][r] * 0.17677669529663687f + bias + ((ridr==ridc) ? 0.f : -100.f);
      }
      float mx = fmaxf(fmaxf(vals[0],vals[1]), fmaxf(vals[2],vals[3]));
      #pragma unroll
      for (int d=1; d<16; d<<=1) mx = fmaxf(mx, __shfl_xor(mx, d, 64));
      float sum = 0.f;
      #pragma unroll
      for (int j=0;j<4;j++){ vals[j] = expf(vals[j]-mx); sum += vals[j]; }
      #pragma unroll
      for (int d=1; d<16; d<<=1) sum += __shfl_xor(sum, d, 64);
      float inv = 1.f / sum;
      #pragma unroll
      for (int j=0;j<4;j++){
        int col = j*16 + lr;
        Plds[h*4096 + row*64 + (col ^ ((row & 7) << 3))] = f2bf(vals[j]*inv);
      }
    }
  }

  // PV (each wave reads only its own Plds[h]/Vt[h] regions; within-wave ordering)
  f32x4 oa[4][2];
  #pragma unroll
  for (int i=0;i<4;i++)
    #pragma unroll
    for (int n=0;n<2;n++) oa[i][n] = zero;
  #pragma unroll
  for (int kb=0; kb<2; kb++){
    bhalf8 pf[4], vf[2];
    int k = (kb<<5) + (lg<<3);
    #pragma unroll
    for (int i=0;i<4;i++){
      int row = i*16 + lr;
      pf[i] = *(const bhalf8*)&Plds[h*4096 + row*64 + (k ^ ((row&7)<<3))];
    }
    #pragma unroll
    for (int n=0;n<2;n++){
      int d = n*16 + lr;
      vf[n] = *(const bhalf8*)&Vt[h][d*64 + (k ^ ((d&7)<<3))];
    }
    #pragma unroll
    for (int i=0;i<4;i++)
      #pragma unroll
      for (int n=0;n<2;n++)
        oa[i][n] = __builtin_amdgcn_mfma_f32_16x16x32_bf16(pf[i], vf[n], oa[i][n], 0, 0, 0);
  }

  // ---- fused proj: ctx -> Clds (aliases Plds), then 64x192 @ 192x192 ----
  __syncthreads();                       // all PV reads of Plds done
  u16* Clds = &Plds[0];                  // [64][192], granule-swizzled
  #pragma unroll
  for (int i=0;i<4;i++)
    #pragma unroll
    for (int n=0;n<2;n++)
      #pragma unroll
      for (int r=0;r<4;r++){
        int row = i*16 + lg*4 + r;
        int col = h*32 + n*16 + lr;
        Clds[row*192 + (((col>>3) ^ (row&7)) << 3) + (col & 7)] = f2bf(oa[i][n][r]);
      }
  __syncthreads();                       // ctx complete

  f32x4 pacc[4][2];
  #pragma unroll
  for (int i=0;i<4;i++)
    #pragma unroll
    for (int n=0;n<2;n++) pacc[i][n] = zero;
  #pragma unroll
  for (int kk=0; kk<6; kk++){
    bhalf8 af[4], bf[2];
    #pragma unroll
    for (int i=0;i<4;i++){
      int row = i*16 + lr;
      int gk = (kk*4 + lg) ^ (row & 7);
      af[i] = *(const bhalf8*)&Clds[row*192 + gk*8];
    }
    #pragma unroll
    for (int n=0;n<2;n++){
      int col = h*32 + n*16 + lr;
      bf[n] = *(const bhalf8*)&projWt[(size_t)col*192 + kk*32 + (lg<<3)];
    }
    #pragma unroll
    for (int i=0;i<4;i++)
      #pragma unroll
      for (int n=0;n<2;n++)
        pacc[i][n] = __builtin_amdgcn_mfma_f32_16x16x32_bf16(af[i], bf[n], pacc[i][n], 0, 0, 0);
  }
  #pragma unroll
  for (int i=0;i<4;i++)
    #pragma unroll
    for (int n=0;n<2;n++){
      int col = h*32 + n*16 + lr;
      float bv = proj_b[col];
      #pragma unroll
      for (int r=0;r<4;r++){
        int rowl = i*16 + lg*4 + r;
        int g = tok2glob(widx*64 + rowl);
        size_t o = (size_t)g*192 + col;
        out[o] = x[o] + bv + pacc[i][n][r];
      }
    }
}

extern "C" void kernel_launch(void* const* d_in, const int* in_sizes, int n_in,
                              void* d_out, int out_size, void* d_ws, size_t ws_size,
                              hipStream_t stream){
  const float* x      = (const float*)d_in[0];
  const float* n1g    = (const float*)d_in[1];
  const float* n1b    = (const float*)d_in[2];
  const float* qkv_w  = (const float*)d_in[3];
  const float* qkv_b  = (const float*)d_in[4];
  const float* proj_w = (const float*)d_in[5];
  const float* proj_b = (const float*)d_in[6];
  const float* rpb    = (const float*)d_in[7];
  const float* n2g    = (const float*)d_in[8];
  const float* n2b    = (const float*)d_in[9];
  const float* fc1_w  = (const float*)d_in[10];
  const float* fc1_b  = (const float*)d_in[11];
  const float* fc2_w  = (const float*)d_in[12];
  const float* fc2_b  = (const float*)d_in[13];
  float* out = (float*)d_out;

  const size_t T = (size_t)T_TOK;
  u16* QKV  = (u16*)d_ws;            // T*576; H1 (T*768) aliases same region
  u16* H1   = QKV;                   // reused after attn consumes QKV
  u16* WT   = QKV + T*768;
  u16* qkvWt  = WT;
  u16* projWt = qkvWt + 576*192;
  u16* fc1Wt  = projWt + 192*192;
  u16* fc2Wt  = fc1Wt + 768*192;

  transcast_kernel<<<dim3((192*576+255)/256),256,0,stream>>>(qkv_w, qkvWt, 192, 576);
  transcast_kernel<<<dim3((192*192+255)/256),256,0,stream>>>(proj_w, projWt, 192, 192);
  transcast_kernel<<<dim3((192*768+255)/256),256,0,stream>>>(fc1_w, fc1Wt, 192, 768);
  transcast_kernel<<<dim3((768*192+255)/256),256,0,stream>>>(fc2_w, fc2Wt, 768, 192);

  // LN1 + qkv GEMM (gathered rows), N=576
  gemm_ln_kernel<1,0><<<dim3(1024),256,0,stream>>>(x, n1g, n1b, qkvWt, qkv_b, QKV, 9);
  // attention + proj + residual -> out (xmid)
  attn_proj_kernel<<<dim3(2048),384,0,stream>>>(QKV, projWt, proj_b, x, out, rpb);
  // LN2 + fc1 GEMM + gelu, N=768
  gemm_ln_kernel<0,1><<<dim3(1024),256,0,stream>>>(out, n2g, n2b, fc1Wt, fc1_b, H1, 12);
  // fc2 + residual (in-place on out)
  fc2_kernel<<<dim3(1024),512,0,stream>>>(H1, fc2Wt, fc2_b, out);
}

// Round 4
// 551.324 us; speedup vs baseline: 1.1942x; 1.1515x over previous
//
#include <hip/hip_runtime.h>
#include <hip/hip_bf16.h>

// Swin block, MI355X. v4: gemm_ln rewritten — BM=64, A-tile hoisted to registers,
// swapped-operand MFMA for packed 8B stores, unrolled barrier-free N-loop.
// B=32 H=W=64 C=192 WS=8 SS=4 NH=6 Dh=32 N=64 nW=64; T = 131072 tokens.

#define DI __device__ __forceinline__

typedef __attribute__((ext_vector_type(8))) short bhalf8;   // 8 bf16 (4 VGPR)
typedef __attribute__((ext_vector_type(4))) float f32x4;
typedef unsigned short u16;
typedef unsigned int   u32;

DI u16 f2bf(float f){                       // RNE f32->bf16
  union { float f; u32 u; } v; v.f = f;
  u32 r = v.u + 0x7FFFu + ((v.u >> 16) & 1u);
  return (u16)(r >> 16);
}
DI u32 f2bf2(float a, float b){ return (u32)f2bf(a) | ((u32)f2bf(b) << 16); }

static const int T_TOK = 131072;

// window-token index t -> global token g (shift+partition map; same for gather & scatter)
DI int tok2glob(int t){
  int n = t & 63, widx = t >> 6;
  int b = widx >> 6, wi = widx & 63;
  int hh = ((wi >> 3) << 3) + (n >> 3);
  int ww = ((wi & 7) << 3) + (n & 7);
  int hs = (hh + 4) & 63, wsv = (ww + 4) & 63;
  return (b << 12) + (hs << 6) + wsv;
}

// ------------- weight prep: W(K,N) fp32 -> Wt(N,K) bf16 -------------
__global__ void transcast_kernel(const float* __restrict__ W, u16* __restrict__ Wt, int K, int N){
  int idx = blockIdx.x * 256 + threadIdx.x;
  if (idx < K*N){
    int n = idx / K, k = idx - n*K;
    Wt[idx] = f2bf(W[(size_t)k * N + n]);
  }
}

// ---------------- fused LN + GEMM, K=192, M-tile 64, unrolled N-loop ----------------
// out[M x NT*64] (bf16) = act( LN(X[gather]) @ Wt^T + bias ),  act = id or gelu
// 4 waves; wave w owns col-chunk nt*64 + w*16 per tile. A-tile fully in registers.
template<int PERM, int GELU, int NT>
__global__ __launch_bounds__(256) void gemm_ln_kernel(
    const float* __restrict__ X, const float* __restrict__ gam, const float* __restrict__ bet,
    const u16* __restrict__ Bt, const float* __restrict__ bias, u16* __restrict__ outH){
  __shared__ u16 As[64*192];                       // 24 KB, granule-swizzled
  int tid = threadIdx.x;
  int mBase = blockIdx.x << 6;

  // ---- LN staging: 64 rows, 4 threads per row (48 f32 each) ----
  {
    int qrow = tid >> 2, quarter = tid & 3;
    int t = mBase + qrow;
    int g = PERM ? tok2glob(t) : t;
    const float4* xr = (const float4*)(X + (size_t)g*192 + quarter*48);
    float4 va[12];
    float s = 0.f, sq = 0.f;
    #pragma unroll
    for (int j = 0; j < 12; j++){
      va[j] = xr[j];
      s  += va[j].x + va[j].y + va[j].z + va[j].w;
      sq += va[j].x*va[j].x + va[j].y*va[j].y + va[j].z*va[j].z + va[j].w*va[j].w;
    }
    s  += __shfl_xor(s, 1, 64);  sq += __shfl_xor(sq, 1, 64);
    s  += __shfl_xor(s, 2, 64);  sq += __shfl_xor(sq, 2, 64);
    float mean = s * (1.f/192.f);
    float rstd = rsqrtf(sq * (1.f/192.f) - mean*mean + 1e-5f);
    const float4* g4 = (const float4*)(gam + quarter*48);
    const float4* b4 = (const float4*)(bet + quarter*48);
    #pragma unroll
    for (int j2 = 0; j2 < 6; j2++){
      float4 v0 = va[2*j2], v1 = va[2*j2+1];
      float4 g0 = g4[2*j2], g1 = g4[2*j2+1];
      float4 b0 = b4[2*j2], b1 = b4[2*j2+1];
      uint4 pk;
      pk.x = f2bf2((v0.x-mean)*rstd*g0.x+b0.x, (v0.y-mean)*rstd*g0.y+b0.y);
      pk.y = f2bf2((v0.z-mean)*rstd*g0.z+b0.z, (v0.w-mean)*rstd*g0.w+b0.w);
      pk.z = f2bf2((v1.x-mean)*rstd*g1.x+b1.x, (v1.y-mean)*rstd*g1.y+b1.y);
      pk.w = f2bf2((v1.z-mean)*rstd*g1.z+b1.z, (v1.w-mean)*rstd*g1.w+b1.w);
      int gk = quarter*6 + j2;                     // 24 granules/row
      *(uint4*)&As[qrow*192 + ((gk ^ (qrow & 7)) << 3)] = pk;
    }
  }
  __syncthreads();

  int lane = tid & 63, w = tid >> 6;
  int lr = lane & 15, lg = lane >> 4;

  // ---- hoist token fragments (B-slot operand): all 64 rows x K=192 in regs ----
  bhalf8 tF[4][6];                                 // [i][kk]: token=i*16+lr, k=kk*32+lg*8
  #pragma unroll
  for (int i = 0; i < 4; i++)
    #pragma unroll
    for (int kk = 0; kk < 6; kk++){
      int row = i*16 + lr;
      tF[i][kk] = *(const bhalf8*)&As[row*192 + (((kk*4 + lg) ^ (row & 7)) << 3)];
    }

  const int ldo = NT << 6;
  #pragma unroll
  for (int nt = 0; nt < NT; nt++){
    int cBase = (nt << 6) + (w << 4);              // wave's 16-col channel chunk
    // weight fragments (A-slot): channel = cBase+lr, k = kk*32+lg*8
    bhalf8 wF[6];
    #pragma unroll
    for (int kk = 0; kk < 6; kk++)
      wF[kk] = *(const bhalf8*)&Bt[(size_t)(cBase + lr)*192 + kk*32 + (lg<<3)];
    float4 bv = *(const float4*)&bias[cBase + (lg<<2)];
    #pragma unroll
    for (int i = 0; i < 4; i++){
      f32x4 a0 = (f32x4){0.f,0.f,0.f,0.f}, a1 = (f32x4){0.f,0.f,0.f,0.f};
      #pragma unroll
      for (int kk = 0; kk < 3; kk++){
        a0 = __builtin_amdgcn_mfma_f32_16x16x32_bf16(wF[2*kk],   tF[i][2*kk],   a0, 0, 0, 0);
        a1 = __builtin_amdgcn_mfma_f32_16x16x32_bf16(wF[2*kk+1], tF[i][2*kk+1], a1, 0, 0, 0);
      }
      // D: token = i*16+lr, channels = cBase + lg*4 + r  -> one 8B packed store
      float v0 = a0[0]+a1[0]+bv.x, v1 = a0[1]+a1[1]+bv.y;
      float v2 = a0[2]+a1[2]+bv.z, v3 = a0[3]+a1[3]+bv.w;
      if (GELU){
        v0 = 0.5f*v0*(1.0f+erff(v0*0.70710678118654752f));
        v1 = 0.5f*v1*(1.0f+erff(v1*0.70710678118654752f));
        v2 = 0.5f*v2*(1.0f+erff(v2*0.70710678118654752f));
        v3 = 0.5f*v3*(1.0f+erff(v3*0.70710678118654752f));
      }
      uint2 pk; pk.x = f2bf2(v0, v1); pk.y = f2bf2(v2, v3);
      int row = mBase + i*16 + lr;
      *(uint2*)&outH[(size_t)row * ldo + cBase + (lg<<2)] = pk;
    }
  }
}

// ---------------- fc2: C(M,192) = A(M,768) @ Wt(192,768)^T + residual ----------------
// 512 threads, wave grid 2M x 4N (each wave 64x48), A double-buffered, B from L2.
// Swapped-operand MFMA: thread holds 4 consecutive channels -> float4 RMW epilogue.
__global__ __launch_bounds__(512) void fc2_kernel(const u16* __restrict__ A,
    const u16* __restrict__ Bt, const float* __restrict__ bias, float* __restrict__ out){
  __shared__ u16 As[2][128*64];
  int tid = threadIdx.x, mBase = blockIdx.x << 7;
  int lane = tid & 63, w = tid >> 6;
  int wm = w >> 2, wn = w & 3, lr = lane & 15, lg = lane >> 4;
  int r0 = tid >> 3, ko = (tid & 7) << 3;
  f32x4 acc[4][3];
  #pragma unroll
  for (int i=0;i<4;i++)
    #pragma unroll
    for (int n=0;n<3;n++) acc[i][n] = (f32x4){0.f,0.f,0.f,0.f};

  // stage kb=0
  #pragma unroll
  for (int it=0; it<2; it++){
    int row = r0 + it*64;
    uint4 v = *(const uint4*)&A[(size_t)(mBase + row)*768 + ko];
    *(uint4*)&As[0][row*64 + ((((ko>>3) ^ (row&7))) << 3)] = v;
  }

  for (int kb = 0; kb < 12; kb++){
    __syncthreads();
    int cur = kb & 1, nxt = cur ^ 1;
    if (kb < 11){
      #pragma unroll
      for (int it=0; it<2; it++){
        int row = r0 + it*64;
        uint4 v = *(const uint4*)&A[(size_t)(mBase + row)*768 + (kb+1)*64 + ko];
        *(uint4*)&As[nxt][row*64 + ((((ko>>3) ^ (row&7))) << 3)] = v;
      }
    }
    bhalf8 bF[2][3];
    #pragma unroll
    for (int kk=0; kk<2; kk++)
      #pragma unroll
      for (int n=0; n<3; n++){
        int col = wn*48 + n*16 + lr;
        bF[kk][n] = *(const bhalf8*)&Bt[(size_t)col*768 + kb*64 + kk*32 + (lg<<3)];
      }
    #pragma unroll
    for (int kk=0; kk<2; kk++){
      bhalf8 aF[4];
      #pragma unroll
      for (int i=0;i<4;i++){
        int row = wm*64 + i*16 + lr;
        aF[i] = *(const bhalf8*)&As[cur][row*64 + (((kk*4 + lg) ^ (row&7)) << 3)];
      }
      #pragma unroll
      for (int i=0;i<4;i++)
        #pragma unroll
        for (int n=0;n<3;n++)
          acc[i][n] = __builtin_amdgcn_mfma_f32_16x16x32_bf16(bF[kk][n], aF[i], acc[i][n], 0, 0, 0);
    }
  }
  // epilogue: token = wm*64+i*16+lr, channels = wn*48+n*16+lg*4+{0..3}
  #pragma unroll
  for (int i=0;i<4;i++)
    #pragma unroll
    for (int n=0;n<3;n++){
      int col = wn*48 + n*16 + (lg<<2);
      float4 bv = *(const float4*)&bias[col];
      int row = mBase + wm*64 + i*16 + lr;
      float4* op = (float4*)&out[(size_t)row*192 + col];
      float4 o = *op;
      o.x += bv.x + acc[i][n][0];
      o.y += bv.y + acc[i][n][1];
      o.z += bv.z + acc[i][n][2];
      o.w += bv.w + acc[i][n][3];
      *op = o;
    }
}

// ---------------- windowed attention + proj + residual: 1 block/window ----------------
DI int region_id(int hpos, int wpos){
  int rh = (hpos < 56) ? 0 : ((hpos < 60) ? 1 : 2);
  int rw = (wpos < 56) ? 0 : ((wpos < 60) ? 1 : 2);
  return rh*3 + rw;
}

__global__ __launch_bounds__(384) void attn_proj_kernel(const u16* __restrict__ QKV,
    const u16* __restrict__ projWt, const float* __restrict__ proj_b,
    const float* __restrict__ x, float* __restrict__ out, const float* __restrict__ rpb){
  __shared__ u16 Plds[6*64*64];   // P (per head), later aliased as Clds[64][192]
  __shared__ u16 Vt[6][32*64];    // V^T, XOR-swizzled
  __shared__ float Rlds[225*6];
  int widx = blockIdx.x;
  int h = threadIdx.x >> 6, lane = threadIdx.x & 63;
  int lr = lane & 15, lg = lane >> 4;

  for (int i = threadIdx.x; i < 225*6; i += 384) Rlds[i] = rpb[i];

  { // stage V transposed: lane = token
    const uint4* vp4 = (const uint4*)(QKV + (size_t)(widx*64 + lane)*576 + 384 + h*32);
    #pragma unroll
    for (int q4 = 0; q4 < 4; q4++){
      union { uint4 v; u16 s[8]; } u; u.v = vp4[q4];
      #pragma unroll
      for (int j = 0; j < 8; j++){
        int d = q4*8 + j;
        Vt[h][d*64 + (lane ^ ((d & 7) << 3))] = u.s[j];
      }
    }
  }

  bhalf8 qf[4], kf[4];
  #pragma unroll
  for (int i=0;i<4;i++){
    int row = i*16 + lr;
    qf[i] = *(const bhalf8*)(QKV + (size_t)(widx*64 + row)*576 + h*32 + (lg<<3));
  }
  #pragma unroll
  for (int j=0;j<4;j++){
    int col = j*16 + lr;
    kf[j] = *(const bhalf8*)(QKV + (size_t)(widx*64 + col)*576 + 192 + h*32 + (lg<<3));
  }
  f32x4 sc[4][4];
  f32x4 zero = (f32x4){0.f,0.f,0.f,0.f};
  #pragma unroll
  for (int i=0;i<4;i++)
    #pragma unroll
    for (int j=0;j<4;j++)
      sc[i][j] = __builtin_amdgcn_mfma_f32_16x16x32_bf16(qf[i], kf[j], zero, 0, 0, 0);

  __syncthreads();   // Rlds ready

  int mwin = widx >> 5;                 // faithful to reference reshape quirk
  int mh0 = (mwin >> 3) << 3, mw0 = (mwin & 7) << 3;
  #pragma unroll
  for (int i=0;i<4;i++){
    #pragma unroll
    for (int r=0;r<4;r++){
      int row = i*16 + lg*4 + r;
      int ih = row >> 3, iw = row & 7;
      int ridr = region_id(mh0 + ih, mw0 + iw);
      float vals[4];
      #pragma unroll
      for (int j=0;j<4;j++){
        int col = j*16 + lr;
        int jh = col >> 3, jw = col & 7;
        float bias = Rlds[((ih-jh+7)*15 + (iw-jw+7))*6 + h];
        int ridc = region_id(mh0 + jh, mw0 + jw);
        vals[j] = sc[i][j][r] * 0.17677669529663687f + bias + ((ridr==ridc) ? 0.f : -100.f);
      }
      float mx = fmaxf(fmaxf(vals[0],vals[1]), fmaxf(vals[2],vals[3]));
      #pragma unroll
      for (int d=1; d<16; d<<=1) mx = fmaxf(mx, __shfl_xor(mx, d, 64));
      float sum = 0.f;
      #pragma unroll
      for (int j=0;j<4;j++){ vals[j] = expf(vals[j]-mx); sum += vals[j]; }
      #pragma unroll
      for (int d=1; d<16; d<<=1) sum += __shfl_xor(sum, d, 64);
      float inv = 1.f / sum;
      #pragma unroll
      for (int j=0;j<4;j++){
        int col = j*16 + lr;
        Plds[h*4096 + row*64 + (col ^ ((row & 7) << 3))] = f2bf(vals[j]*inv);
      }
    }
  }

  // PV (each wave reads only its own Plds[h]/Vt[h] regions; within-wave ordering)
  f32x4 oa[4][2];
  #pragma unroll
  for (int i=0;i<4;i++)
    #pragma unroll
    for (int n=0;n<2;n++) oa[i][n] = zero;
  #pragma unroll
  for (int kb=0; kb<2; kb++){
    bhalf8 pf[4], vf[2];
    int k = (kb<<5) + (lg<<3);
    #pragma unroll
    for (int i=0;i<4;i++){
      int row = i*16 + lr;
      pf[i] = *(const bhalf8*)&Plds[h*4096 + row*64 + (k ^ ((row&7)<<3))];
    }
    #pragma unroll
    for (int n=0;n<2;n++){
      int d = n*16 + lr;
      vf[n] = *(const bhalf8*)&Vt[h][d*64 + (k ^ ((d&7)<<3))];
    }
    #pragma unroll
    for (int i=0;i<4;i++)
      #pragma unroll
      for (int n=0;n<2;n++)
        oa[i][n] = __builtin_amdgcn_mfma_f32_16x16x32_bf16(pf[i], vf[n], oa[i][n], 0, 0, 0);
  }

  // ---- fused proj: ctx -> Clds (aliases Plds), then 64x192 @ 192x192 ----
  __syncthreads();                       // all PV reads of Plds done
  u16* Clds = &Plds[0];                  // [64][192], granule-swizzled
  #pragma unroll
  for (int i=0;i<4;i++)
    #pragma unroll
    for (int n=0;n<2;n++)
      #pragma unroll
      for (int r=0;r<4;r++){
        int row = i*16 + lg*4 + r;
        int col = h*32 + n*16 + lr;
        Clds[row*192 + (((col>>3) ^ (row&7)) << 3) + (col & 7)] = f2bf(oa[i][n][r]);
      }
  __syncthreads();                       // ctx complete

  f32x4 pacc[4][2];
  #pragma unroll
  for (int i=0;i<4;i++)
    #pragma unroll
    for (int n=0;n<2;n++) pacc[i][n] = zero;
  #pragma unroll
  for (int kk=0; kk<6; kk++){
    bhalf8 af[4], bf[2];
    #pragma unroll
    for (int i=0;i<4;i++){
      int row = i*16 + lr;
      int gk = (kk*4 + lg) ^ (row & 7);
      af[i] = *(const bhalf8*)&Clds[row*192 + gk*8];
    }
    #pragma unroll
    for (int n=0;n<2;n++){
      int col = h*32 + n*16 + lr;
      bf[n] = *(const bhalf8*)&projWt[(size_t)col*192 + kk*32 + (lg<<3)];
    }
    #pragma unroll
    for (int i=0;i<4;i++)
      #pragma unroll
      for (int n=0;n<2;n++)
        pacc[i][n] = __builtin_amdgcn_mfma_f32_16x16x32_bf16(af[i], bf[n], pacc[i][n], 0, 0, 0);
  }
  #pragma unroll
  for (int i=0;i<4;i++)
    #pragma unroll
    for (int n=0;n<2;n++){
      int col = h*32 + n*16 + lr;
      float bv = proj_b[col];
      #pragma unroll
      for (int r=0;r<4;r++){
        int rowl = i*16 + lg*4 + r;
        int g = tok2glob(widx*64 + rowl);
        size_t o = (size_t)g*192 + col;
        out[o] = x[o] + bv + pacc[i][n][r];
      }
    }
}

extern "C" void kernel_launch(void* const* d_in, const int* in_sizes, int n_in,
                              void* d_out, int out_size, void* d_ws, size_t ws_size,
                              hipStream_t stream){
  const float* x      = (const float*)d_in[0];
  const float* n1g    = (const float*)d_in[1];
  const float* n1b    = (const float*)d_in[2];
  const float* qkv_w  = (const float*)d_in[3];
  const float* qkv_b  = (const float*)d_in[4];
  const float* proj_w = (const float*)d_in[5];
  const float* proj_b = (const float*)d_in[6];
  const float* rpb    = (const float*)d_in[7];
  const float* n2g    = (const float*)d_in[8];
  const float* n2b    = (const float*)d_in[9];
  const float* fc1_w  = (const float*)d_in[10];
  const float* fc1_b  = (const float*)d_in[11];
  const float* fc2_w  = (const float*)d_in[12];
  const float* fc2_b  = (const float*)d_in[13];
  float* out = (float*)d_out;

  const size_t T = (size_t)T_TOK;
  u16* QKV  = (u16*)d_ws;            // T*576; H1 (T*768) aliases same region
  u16* H1   = QKV;                   // reused after attn consumes QKV
  u16* WT   = QKV + T*768;
  u16* qkvWt  = WT;
  u16* projWt = qkvWt + 576*192;
  u16* fc1Wt  = projWt + 192*192;
  u16* fc2Wt  = fc1Wt + 768*192;

  transcast_kernel<<<dim3((192*576+255)/256),256,0,stream>>>(qkv_w, qkvWt, 192, 576);
  transcast_kernel<<<dim3((192*192+255)/256),256,0,stream>>>(proj_w, projWt, 192, 192);
  transcast_kernel<<<dim3((192*768+255)/256),256,0,stream>>>(fc1_w, fc1Wt, 192, 768);
  transcast_kernel<<<dim3((768*192+255)/256),256,0,stream>>>(fc2_w, fc2Wt, 768, 192);

  // LN1 + qkv GEMM (gathered rows), N=576
  gemm_ln_kernel<1,0,9><<<dim3(2048),256,0,stream>>>(x, n1g, n1b, qkvWt, qkv_b, QKV);
  // attention + proj + residual -> out (xmid)
  attn_proj_kernel<<<dim3(2048),384,0,stream>>>(QKV, projWt, proj_b, x, out, rpb);
  // LN2 + fc1 GEMM + gelu, N=768
  gemm_ln_kernel<0,1,12><<<dim3(2048),256,0,stream>>>(out, n2g, n2b, fc1Wt, fc1_b, H1);
  // fc2 + residual (in-place on out)
  fc2_kernel<<<dim3(1024),512,0,stream>>>(H1, fc2Wt, fc2_b, out);
}

// Round 5
// 524.493 us; speedup vs baseline: 1.2552x; 1.0512x over previous
//
#include <hip/hip_runtime.h>
#include <hip/hip_bf16.h>

// Swin block, MI355X. v5: two fused kernels.
//  attn_fused: LN1 + qkv GEMM (LDS-resident) + windowed attention + proj + residual
//  mlp_fused : LN2 + fc1 + GELU + fc2 + residual (H1 LDS-resident, 2 half-passes)
// B=32 H=W=64 C=192 WS=8 SS=4 NH=6 Dh=32 N=64 nW=64; T = 131072 tokens.

#define DI __device__ __forceinline__

typedef __attribute__((ext_vector_type(8))) short bhalf8;   // 8 bf16 (4 VGPR)
typedef __attribute__((ext_vector_type(4))) float f32x4;
typedef unsigned short u16;
typedef unsigned int   u32;

DI u16 f2bf(float f){                       // RNE f32->bf16
  union { float f; u32 u; } v; v.f = f;
  u32 r = v.u + 0x7FFFu + ((v.u >> 16) & 1u);
  return (u16)(r >> 16);
}
DI u32 f2bf2(float a, float b){ return (u32)f2bf(a) | ((u32)f2bf(b) << 16); }

// gelu(x)=0.5x(1+erf(x/sqrt2)); erf via Abramowitz-Stegun 7.1.26 (|err|<1.5e-7)
DI float fast_gelu(float x){
  float ax = fabsf(x) * 0.70710678118654752f;
  float t = 1.0f / fmaf(0.3275911f, ax, 1.0f);
  float poly = t*(0.254829592f + t*(-0.284496736f + t*(1.421413741f +
               t*(-1.453152027f + t*1.061405429f))));
  float erfv = 1.0f - poly * __expf(-ax*ax);
  erfv = (x < 0.f) ? -erfv : erfv;
  return 0.5f * x * (1.0f + erfv);
}

// window-token index t -> global token g (shift+partition map; gather & scatter identical)
DI int tok2glob(int t){
  int n = t & 63, widx = t >> 6;
  int b = widx >> 6, wi = widx & 63;
  int hh = ((wi >> 3) << 3) + (n >> 3);
  int ww = ((wi & 7) << 3) + (n & 7);
  int hs = (hh + 4) & 63, wsv = (ww + 4) & 63;
  return (b << 12) + (hs << 6) + wsv;
}

DI int region_id(int hpos, int wpos){
  int rh = (hpos < 56) ? 0 : ((hpos < 60) ? 1 : 2);
  int rw = (wpos < 56) ? 0 : ((wpos < 60) ? 1 : 2);
  return rh*3 + rw;
}

// ------------- weight prep: W(K,N) fp32 -> Wt(N,K) bf16 -------------
__global__ void transcast_kernel(const float* __restrict__ W, u16* __restrict__ Wt, int K, int N){
  int idx = blockIdx.x * 256 + threadIdx.x;
  if (idx < K*N){
    int n = idx / K, k = idx - n*K;
    Wt[idx] = f2bf(W[(size_t)k * N + n]);
  }
}

// =================== attn_fused: 1 block / window, 384 threads ===================
__global__ __launch_bounds__(384) void attn_fused_kernel(
    const float* __restrict__ x, const float* __restrict__ n1g, const float* __restrict__ n1b,
    const u16* __restrict__ qkvWt, const float* __restrict__ qkv_b,
    const u16* __restrict__ projWt, const float* __restrict__ proj_b,
    float* __restrict__ out, const float* __restrict__ rpb){
  __shared__ u16 AsB[64*192];      // 24 KB: LN'd tokens; later aliased as Clds
  __shared__ u16 QKB[64*384];      // 48 KB: Q|K tiles; later aliased as P (6 x 64x64)
  __shared__ u16 Vt[6][32*64];     // 24 KB: V^T per head, XOR-swizzled
  __shared__ float Rlds[225*6];
  int widx = blockIdx.x;
  int tid  = threadIdx.x;
  int h = tid >> 6, lane = tid & 63, lr = lane & 15, lg = lane >> 4;

  if (h >= 4){                     // waves 4-5: stage rel-pos bias
    for (int i = tid - 256; i < 225*6; i += 128) Rlds[i] = rpb[i];
  } else {                         // waves 0-3: LN1, 4 threads/row
    int qrow = tid >> 2, quarter = tid & 3;
    int g = tok2glob(widx*64 + qrow);
    const float4* xr = (const float4*)(x + (size_t)g*192 + quarter*48);
    float4 va[12];
    float s = 0.f, sq = 0.f;
    #pragma unroll
    for (int j = 0; j < 12; j++){
      va[j] = xr[j];
      s  += va[j].x + va[j].y + va[j].z + va[j].w;
      sq += va[j].x*va[j].x + va[j].y*va[j].y + va[j].z*va[j].z + va[j].w*va[j].w;
    }
    s  += __shfl_xor(s, 1, 64);  sq += __shfl_xor(sq, 1, 64);
    s  += __shfl_xor(s, 2, 64);  sq += __shfl_xor(sq, 2, 64);
    float mean = s * (1.f/192.f);
    float rstd = rsqrtf(sq * (1.f/192.f) - mean*mean + 1e-5f);
    const float4* g4 = (const float4*)(n1g + quarter*48);
    const float4* b4 = (const float4*)(n1b + quarter*48);
    #pragma unroll
    for (int j2 = 0; j2 < 6; j2++){
      float4 v0 = va[2*j2], v1 = va[2*j2+1];
      float4 g0 = g4[2*j2], g1 = g4[2*j2+1];
      float4 b0 = b4[2*j2], b1 = b4[2*j2+1];
      uint4 pk;
      pk.x = f2bf2((v0.x-mean)*rstd*g0.x+b0.x, (v0.y-mean)*rstd*g0.y+b0.y);
      pk.y = f2bf2((v0.z-mean)*rstd*g0.z+b0.z, (v0.w-mean)*rstd*g0.w+b0.w);
      pk.z = f2bf2((v1.x-mean)*rstd*g1.x+b1.x, (v1.y-mean)*rstd*g1.y+b1.y);
      pk.w = f2bf2((v1.z-mean)*rstd*g1.z+b1.z, (v1.w-mean)*rstd*g1.w+b1.w);
      int gk = quarter*6 + j2;
      *(uint4*)&AsB[qrow*192 + ((gk ^ (qrow & 7)) << 3)] = pk;
    }
  }
  __syncthreads();                 // AsB + Rlds ready

  // ---- qkv GEMM: wave h computes output cols [h*96, h*96+96) ----
  // waves 0-3 -> Q|K (cols 0..384) into QKB; waves 4-5 -> V (cols 384..576) into Vt
  #pragma unroll
  for (int nf = 0; nf < 6; nf++){
    int cBase = h*96 + nf*16;
    bhalf8 wF[6];
    #pragma unroll
    for (int kk = 0; kk < 6; kk++)
      wF[kk] = *(const bhalf8*)&qkvWt[(size_t)(cBase + lr)*192 + kk*32 + (lg<<3)];
    float4 bv = *(const float4*)&qkv_b[cBase + (lg<<2)];
    #pragma unroll
    for (int i = 0; i < 4; i++){
      f32x4 a0 = (f32x4){0.f,0.f,0.f,0.f}, a1 = (f32x4){0.f,0.f,0.f,0.f};
      #pragma unroll
      for (int kk = 0; kk < 3; kk++){
        int row = i*16 + lr;
        bhalf8 t0 = *(const bhalf8*)&AsB[row*192 + (((2*kk*4   + lg) ^ (row & 7)) << 3)];
        bhalf8 t1 = *(const bhalf8*)&AsB[row*192 + ((((2*kk+1)*4 + lg) ^ (row & 7)) << 3)];
        a0 = __builtin_amdgcn_mfma_f32_16x16x32_bf16(wF[2*kk],   t0, a0, 0, 0, 0);
        a1 = __builtin_amdgcn_mfma_f32_16x16x32_bf16(wF[2*kk+1], t1, a1, 0, 0, 0);
      }
      float v0 = a0[0]+a1[0]+bv.x, v1 = a0[1]+a1[1]+bv.y;
      float v2 = a0[2]+a1[2]+bv.z, v3 = a0[3]+a1[3]+bv.w;
      int token = i*16 + lr;
      if (cBase < 384){            // Q|K: packed uint2 into swizzled QKB
        int gq = (cBase >> 3) + (lg >> 1);
        uint2 pk; pk.x = f2bf2(v0, v1); pk.y = f2bf2(v2, v3);
        *(uint2*)&QKB[token*384 + ((gq ^ (token & 7)) << 3) + ((lg & 1) << 2)] = pk;
      } else {                     // V: transposed scatter into Vt
        int d0 = cBase + (lg<<2) - 384;
        int hv = d0 >> 5;
        int db = d0 & 31;
        Vt[hv][(db+0)*64 + (token ^ (((db+0)&7)<<3))] = f2bf(v0);
        Vt[hv][(db+1)*64 + (token ^ (((db+1)&7)<<3))] = f2bf(v1);
        Vt[hv][(db+2)*64 + (token ^ (((db+2)&7)<<3))] = f2bf(v2);
        Vt[hv][(db+3)*64 + (token ^ (((db+3)&7)<<3))] = f2bf(v3);
      }
    }
  }
  __syncthreads();                 // QKB + Vt complete

  // ---- scores: wave h = head h ----
  bhalf8 qf[4], kf[4];
  #pragma unroll
  for (int i = 0; i < 4; i++){
    int token = i*16 + lr;
    int g = h*4 + lg;
    qf[i] = *(const bhalf8*)&QKB[token*384 + ((g ^ (token & 7)) << 3)];
  }
  #pragma unroll
  for (int j = 0; j < 4; j++){
    int token = j*16 + lr;
    int g = 24 + h*4 + lg;
    kf[j] = *(const bhalf8*)&QKB[token*384 + ((g ^ (token & 7)) << 3)];
  }
  f32x4 sc[4][4];
  f32x4 zero = (f32x4){0.f,0.f,0.f,0.f};
  #pragma unroll
  for (int i = 0; i < 4; i++)
    #pragma unroll
    for (int j = 0; j < 4; j++)
      sc[i][j] = __builtin_amdgcn_mfma_f32_16x16x32_bf16(qf[i], kf[j], zero, 0, 0, 0);
  __syncthreads();                 // all QKB reads done -> safe to overwrite with P

  // ---- softmax (+rel-pos bias +shift mask), P into QKB region ----
  u16* Plds = &QKB[0];
  int mwin = widx >> 5;            // faithful to reference reshape quirk
  int mh0 = (mwin >> 3) << 3, mw0 = (mwin & 7) << 3;
  #pragma unroll
  for (int i = 0; i < 4; i++){
    #pragma unroll
    for (int r = 0; r < 4; r++){
      int row = i*16 + lg*4 + r;
      int ih = row >> 3, iw = row & 7;
      int ridr = region_id(mh0 + ih, mw0 + iw);
      float vals[4];
      #pragma unroll
      for (int j = 0; j < 4; j++){
        int col = j*16 + lr;
        int jh = col >> 3, jw = col & 7;
        float bias = Rlds[((ih-jh+7)*15 + (iw-jw+7))*6 + h];
        int ridc = region_id(mh0 + jh, mw0 + jw);
        vals[j] = sc[i][j][r] * 0.17677669529663687f + bias + ((ridr==ridc) ? 0.f : -100.f);
      }
      float mx = fmaxf(fmaxf(vals[0],vals[1]), fmaxf(vals[2],vals[3]));
      #pragma unroll
      for (int d = 1; d < 16; d <<= 1) mx = fmaxf(mx, __shfl_xor(mx, d, 64));
      float sum = 0.f;
      #pragma unroll
      for (int j = 0; j < 4; j++){ vals[j] = __expf(vals[j]-mx); sum += vals[j]; }
      #pragma unroll
      for (int d = 1; d < 16; d <<= 1) sum += __shfl_xor(sum, d, 64);
      float inv = 1.f / sum;
      #pragma unroll
      for (int j = 0; j < 4; j++){
        int col = j*16 + lr;
        Plds[h*4096 + row*64 + (col ^ ((row & 7) << 3))] = f2bf(vals[j]*inv);
      }
    }
  }

  // ---- PV (wave-local P and Vt reads) ----
  f32x4 oa[4][2];
  #pragma unroll
  for (int i=0;i<4;i++)
    #pragma unroll
    for (int n=0;n<2;n++) oa[i][n] = zero;
  #pragma unroll
  for (int kb = 0; kb < 2; kb++){
    bhalf8 pf[4], vf[2];
    int k = (kb<<5) + (lg<<3);
    #pragma unroll
    for (int i = 0; i < 4; i++){
      int row = i*16 + lr;
      pf[i] = *(const bhalf8*)&Plds[h*4096 + row*64 + (k ^ ((row&7)<<3))];
    }
    #pragma unroll
    for (int n = 0; n < 2; n++){
      int d = n*16 + lr;
      vf[n] = *(const bhalf8*)&Vt[h][d*64 + (k ^ ((d&7)<<3))];
    }
    #pragma unroll
    for (int i=0;i<4;i++)
      #pragma unroll
      for (int n=0;n<2;n++)
        oa[i][n] = __builtin_amdgcn_mfma_f32_16x16x32_bf16(pf[i], vf[n], oa[i][n], 0, 0, 0);
  }

  // ---- ctx -> Clds (aliases AsB; AsB dead since qkv barrier) ----
  u16* Clds = &AsB[0];
  #pragma unroll
  for (int i=0;i<4;i++)
    #pragma unroll
    for (int n=0;n<2;n++)
      #pragma unroll
      for (int r=0;r<4;r++){
        int row = i*16 + lg*4 + r;
        int col = h*32 + n*16 + lr;
        Clds[row*192 + (((col>>3) ^ (row&7)) << 3) + (col & 7)] = f2bf(oa[i][n][r]);
      }
  __syncthreads();                 // ctx complete

  // ---- proj (64x192 @ 192x192) + residual scatter ----
  f32x4 pacc[4][2];
  #pragma unroll
  for (int i=0;i<4;i++)
    #pragma unroll
    for (int n=0;n<2;n++) pacc[i][n] = zero;
  #pragma unroll
  for (int kk = 0; kk < 6; kk++){
    bhalf8 af[4], bf[2];
    #pragma unroll
    for (int i = 0; i < 4; i++){
      int row = i*16 + lr;
      af[i] = *(const bhalf8*)&Clds[row*192 + (((kk*4 + lg) ^ (row & 7)) << 3)];
    }
    #pragma unroll
    for (int n = 0; n < 2; n++){
      int col = h*32 + n*16 + lr;
      bf[n] = *(const bhalf8*)&projWt[(size_t)col*192 + kk*32 + (lg<<3)];
    }
    #pragma unroll
    for (int i=0;i<4;i++)
      #pragma unroll
      for (int n=0;n<2;n++)
        pacc[i][n] = __builtin_amdgcn_mfma_f32_16x16x32_bf16(af[i], bf[n], pacc[i][n], 0, 0, 0);
  }
  #pragma unroll
  for (int i=0;i<4;i++)
    #pragma unroll
    for (int n=0;n<2;n++){
      int col = h*32 + n*16 + lr;
      float bv = proj_b[col];
      #pragma unroll
      for (int r=0;r<4;r++){
        int rowl = i*16 + lg*4 + r;
        int g = tok2glob(widx*64 + rowl);
        size_t o = (size_t)g*192 + col;
        out[o] = x[o] + bv + pacc[i][n][r];
      }
    }
}

// =================== mlp_fused: 64 tokens / block, 512 threads ===================
__global__ __launch_bounds__(512) void mlp_fused_kernel(
    const float* __restrict__ X, const float* __restrict__ n2g, const float* __restrict__ n2b,
    const u16* __restrict__ fc1Wt, const float* __restrict__ fc1_b,
    const u16* __restrict__ fc2Wt, const float* __restrict__ fc2_b,
    float* __restrict__ out){
  __shared__ u16 As[64*192];       // 24 KB
  __shared__ u16 Hb[64*384];       // 48 KB: half of H1 per pass
  int tid = threadIdx.x;
  int mBase = blockIdx.x << 6;

  { // LN2: 8 threads/row, 24 f32 each
    int qrow = tid >> 3, oct = tid & 7;
    const float4* xr = (const float4*)(X + (size_t)(mBase + qrow)*192 + oct*24);
    float4 va[6];
    float s = 0.f, sq = 0.f;
    #pragma unroll
    for (int j = 0; j < 6; j++){
      va[j] = xr[j];
      s  += va[j].x + va[j].y + va[j].z + va[j].w;
      sq += va[j].x*va[j].x + va[j].y*va[j].y + va[j].z*va[j].z + va[j].w*va[j].w;
    }
    s  += __shfl_xor(s, 1, 64);  sq += __shfl_xor(sq, 1, 64);
    s  += __shfl_xor(s, 2, 64);  sq += __shfl_xor(sq, 2, 64);
    s  += __shfl_xor(s, 4, 64);  sq += __shfl_xor(sq, 4, 64);
    float mean = s * (1.f/192.f);
    float rstd = rsqrtf(sq * (1.f/192.f) - mean*mean + 1e-5f);
    const float4* g4 = (const float4*)(n2g + oct*24);
    const float4* b4 = (const float4*)(n2b + oct*24);
    #pragma unroll
    for (int j2 = 0; j2 < 3; j2++){
      float4 v0 = va[2*j2], v1 = va[2*j2+1];
      float4 g0 = g4[2*j2], g1 = g4[2*j2+1];
      float4 b0 = b4[2*j2], b1 = b4[2*j2+1];
      uint4 pk;
      pk.x = f2bf2((v0.x-mean)*rstd*g0.x+b0.x, (v0.y-mean)*rstd*g0.y+b0.y);
      pk.y = f2bf2((v0.z-mean)*rstd*g0.z+b0.z, (v0.w-mean)*rstd*g0.w+b0.w);
      pk.z = f2bf2((v1.x-mean)*rstd*g1.x+b1.x, (v1.y-mean)*rstd*g1.y+b1.y);
      pk.w = f2bf2((v1.z-mean)*rstd*g1.z+b1.z, (v1.w-mean)*rstd*g1.w+b1.w);
      int gk = oct*3 + j2;
      *(uint4*)&As[qrow*192 + ((gk ^ (qrow & 7)) << 3)] = pk;
    }
  }
  __syncthreads();

  int lane = tid & 63, w = tid >> 6;
  int lr = lane & 15, lg = lane >> 4;
  int wm2 = w >> 2, wn2 = w & 3;   // fc2 wave grid: 2M x 4N
  f32x4 acc2[2][3];
  #pragma unroll
  for (int i=0;i<2;i++)
    #pragma unroll
    for (int n=0;n<3;n++) acc2[i][n] = (f32x4){0.f,0.f,0.f,0.f};

  #pragma unroll
  for (int p = 0; p < 2; p++){
    // ---- fc1 half-pass: wave w computes cols [p*384 + w*48, +48) ----
    #pragma unroll
    for (int nf = 0; nf < 3; nf++){
      int cBase = w*48 + nf*16;          // col within half
      int gcol = p*384 + cBase;
      bhalf8 wF[6];
      #pragma unroll
      for (int kk = 0; kk < 6; kk++)
        wF[kk] = *(const bhalf8*)&fc1Wt[(size_t)(gcol + lr)*192 + kk*32 + (lg<<3)];
      float4 bv = *(const float4*)&fc1_b[gcol + (lg<<2)];
      #pragma unroll
      for (int i = 0; i < 4; i++){
        f32x4 a0 = (f32x4){0.f,0.f,0.f,0.f}, a1 = (f32x4){0.f,0.f,0.f,0.f};
        #pragma unroll
        for (int kk = 0; kk < 3; kk++){
          int row = i*16 + lr;
          bhalf8 t0 = *(const bhalf8*)&As[row*192 + (((2*kk*4   + lg) ^ (row & 7)) << 3)];
          bhalf8 t1 = *(const bhalf8*)&As[row*192 + ((((2*kk+1)*4 + lg) ^ (row & 7)) << 3)];
          a0 = __builtin_amdgcn_mfma_f32_16x16x32_bf16(wF[2*kk],   t0, a0, 0, 0, 0);
          a1 = __builtin_amdgcn_mfma_f32_16x16x32_bf16(wF[2*kk+1], t1, a1, 0, 0, 0);
        }
        float v0 = fast_gelu(a0[0]+a1[0]+bv.x);
        float v1 = fast_gelu(a0[1]+a1[1]+bv.y);
        float v2 = fast_gelu(a0[2]+a1[2]+bv.z);
        float v3 = fast_gelu(a0[3]+a1[3]+bv.w);
        int token = i*16 + lr;
        int gq = (cBase >> 3) + (lg >> 1);
        uint2 pk; pk.x = f2bf2(v0, v1); pk.y = f2bf2(v2, v3);
        *(uint2*)&Hb[token*384 + ((gq ^ (token & 7)) << 3) + ((lg & 1) << 2)] = pk;
      }
    }
    __syncthreads();                     // Hb ready

    // ---- fc2 partial accumulate over this K half ----
    #pragma unroll
    for (int kb = 0; kb < 12; kb++){
      bhalf8 hF[2];
      #pragma unroll
      for (int i2 = 0; i2 < 2; i2++){
        int token = wm2*32 + i2*16 + lr;
        int g = kb*4 + lg;
        hF[i2] = *(const bhalf8*)&Hb[token*384 + ((g ^ (token & 7)) << 3)];
      }
      bhalf8 w2F[3];
      #pragma unroll
      for (int nf = 0; nf < 3; nf++){
        int ch = wn2*48 + nf*16 + lr;
        w2F[nf] = *(const bhalf8*)&fc2Wt[(size_t)ch*768 + p*384 + kb*32 + (lg<<3)];
      }
      #pragma unroll
      for (int i2 = 0; i2 < 2; i2++)
        #pragma unroll
        for (int nf = 0; nf < 3; nf++)
          acc2[i2][nf] = __builtin_amdgcn_mfma_f32_16x16x32_bf16(w2F[nf], hF[i2], acc2[i2][nf], 0, 0, 0);
    }
    __syncthreads();                     // fc2 reads done before next pass overwrites Hb
  }

  // ---- epilogue: residual RMW, float4 ----
  #pragma unroll
  for (int i2 = 0; i2 < 2; i2++)
    #pragma unroll
    for (int nf = 0; nf < 3; nf++){
      int col = wn2*48 + nf*16 + (lg<<2);
      float4 bv = *(const float4*)&fc2_b[col];
      int row = mBase + wm2*32 + i2*16 + lr;
      float4* op = (float4*)&out[(size_t)row*192 + col];
      float4 o = *op;
      o.x += bv.x + acc2[i2][nf][0];
      o.y += bv.y + acc2[i2][nf][1];
      o.z += bv.z + acc2[i2][nf][2];
      o.w += bv.w + acc2[i2][nf][3];
      *op = o;
    }
}

extern "C" void kernel_launch(void* const* d_in, const int* in_sizes, int n_in,
                              void* d_out, int out_size, void* d_ws, size_t ws_size,
                              hipStream_t stream){
  const float* x      = (const float*)d_in[0];
  const float* n1g    = (const float*)d_in[1];
  const float* n1b    = (const float*)d_in[2];
  const float* qkv_w  = (const float*)d_in[3];
  const float* qkv_b  = (const float*)d_in[4];
  const float* proj_w = (const float*)d_in[5];
  const float* proj_b = (const float*)d_in[6];
  const float* rpb    = (const float*)d_in[7];
  const float* n2g    = (const float*)d_in[8];
  const float* n2b    = (const float*)d_in[9];
  const float* fc1_w  = (const float*)d_in[10];
  const float* fc1_b  = (const float*)d_in[11];
  const float* fc2_w  = (const float*)d_in[12];
  const float* fc2_b  = (const float*)d_in[13];
  float* out = (float*)d_out;

  u16* qkvWt  = (u16*)d_ws;
  u16* projWt = qkvWt + 576*192;
  u16* fc1Wt  = projWt + 192*192;
  u16* fc2Wt  = fc1Wt + 768*192;

  transcast_kernel<<<dim3((192*576+255)/256),256,0,stream>>>(qkv_w, qkvWt, 192, 576);
  transcast_kernel<<<dim3((192*192+255)/256),256,0,stream>>>(proj_w, projWt, 192, 192);
  transcast_kernel<<<dim3((192*768+255)/256),256,0,stream>>>(fc1_w, fc1Wt, 192, 768);
  transcast_kernel<<<dim3((768*192+255)/256),256,0,stream>>>(fc2_w, fc2Wt, 768, 192);

  // LN1 + qkv + attention + proj + residual -> out (xmid)
  attn_fused_kernel<<<dim3(2048),384,0,stream>>>(x, n1g, n1b, qkvWt, qkv_b,
                                                 projWt, proj_b, out, rpb);
  // LN2 + fc1 + GELU + fc2 + residual (in-place on out)
  mlp_fused_kernel<<<dim3(2048),512,0,stream>>>(out, n2g, n2b, fc1Wt, fc1_b,
                                                fc2Wt, fc2_b, out);
}

// Round 6
// 505.828 us; speedup vs baseline: 1.3016x; 1.0369x over previous
//
#include <hip/hip_runtime.h>
#include <hip/hip_bf16.h>

// Swin block, MI355X. v6: concurrency fix.
//  attn_fused: 12 waves/window (halved per-wave critical path), 1 block/CU but 12 waves resident.
//  mlp_fused : 4-wave 40KB blocks, 6 passes of 128 H-cols -> 4 independent blocks/CU.
// B=32 H=W=64 C=192 WS=8 SS=4 NH=6 Dh=32 N=64 nW=64; T = 131072 tokens.

#define DI __device__ __forceinline__

typedef __attribute__((ext_vector_type(8))) short bhalf8;   // 8 bf16 (4 VGPR)
typedef __attribute__((ext_vector_type(4))) float f32x4;
typedef unsigned short u16;
typedef unsigned int   u32;

DI u16 f2bf(float f){                       // RNE f32->bf16
  union { float f; u32 u; } v; v.f = f;
  u32 r = v.u + 0x7FFFu + ((v.u >> 16) & 1u);
  return (u16)(r >> 16);
}
DI u32 f2bf2(float a, float b){ return (u32)f2bf(a) | ((u32)f2bf(b) << 16); }

// gelu(x)=0.5x(1+erf(x/sqrt2)); erf via Abramowitz-Stegun 7.1.26 (|err|<1.5e-7)
DI float fast_gelu(float x){
  float ax = fabsf(x) * 0.70710678118654752f;
  float t = 1.0f / fmaf(0.3275911f, ax, 1.0f);
  float poly = t*(0.254829592f + t*(-0.284496736f + t*(1.421413741f +
               t*(-1.453152027f + t*1.061405429f))));
  float erfv = 1.0f - poly * __expf(-ax*ax);
  erfv = (x < 0.f) ? -erfv : erfv;
  return 0.5f * x * (1.0f + erfv);
}

// window-token index t -> global token g (shift+partition map; gather & scatter identical)
DI int tok2glob(int t){
  int n = t & 63, widx = t >> 6;
  int b = widx >> 6, wi = widx & 63;
  int hh = ((wi >> 3) << 3) + (n >> 3);
  int ww = ((wi & 7) << 3) + (n & 7);
  int hs = (hh + 4) & 63, wsv = (ww + 4) & 63;
  return (b << 12) + (hs << 6) + wsv;
}

DI int region_id(int hpos, int wpos){
  int rh = (hpos < 56) ? 0 : ((hpos < 60) ? 1 : 2);
  int rw = (wpos < 56) ? 0 : ((wpos < 60) ? 1 : 2);
  return rh*3 + rw;
}

// ------------- weight prep: W(K,N) fp32 -> Wt(N,K) bf16 -------------
__global__ void transcast_kernel(const float* __restrict__ W, u16* __restrict__ Wt, int K, int N){
  int idx = blockIdx.x * 256 + threadIdx.x;
  if (idx < K*N){
    int n = idx / K, k = idx - n*K;
    Wt[idx] = f2bf(W[(size_t)k * N + n]);
  }
}

// =================== attn_fused: 1 block / window, 768 threads (12 waves) ===================
__global__ __launch_bounds__(768, 3) void attn_fused_kernel(
    const float* __restrict__ x, const float* __restrict__ n1g, const float* __restrict__ n1b,
    const u16* __restrict__ qkvWt, const float* __restrict__ qkv_b,
    const u16* __restrict__ projWt, const float* __restrict__ proj_b,
    float* __restrict__ out, const float* __restrict__ rpb){
  __shared__ u16 AsB[64*192];      // 24 KB: LN'd tokens; later aliased as Clds
  __shared__ u16 QKB[64*384];      // 48 KB: Q|K tiles; later aliased as P (6 x 64x64)
  __shared__ u16 Vt[6][32*64];     // 24 KB: V^T per head, XOR-swizzled
  __shared__ float Rlds[225*6];
  int widx = blockIdx.x;
  int tid  = threadIdx.x;
  int w = tid >> 6, lane = tid & 63, lr = lane & 15, lg = lane >> 4;

  if (w >= 8){                     // waves 8-11: stage rel-pos bias
    for (int i = tid - 512; i < 225*6; i += 256) Rlds[i] = rpb[i];
  } else {                         // waves 0-7: LN1, 8 threads/row
    int qrow = tid >> 3, oct = tid & 7;
    int g = tok2glob(widx*64 + qrow);
    const float4* xr = (const float4*)(x + (size_t)g*192 + oct*24);
    float4 va[6];
    float s = 0.f, sq = 0.f;
    #pragma unroll
    for (int j = 0; j < 6; j++){
      va[j] = xr[j];
      s  += va[j].x + va[j].y + va[j].z + va[j].w;
      sq += va[j].x*va[j].x + va[j].y*va[j].y + va[j].z*va[j].z + va[j].w*va[j].w;
    }
    s  += __shfl_xor(s, 1, 64);  sq += __shfl_xor(sq, 1, 64);
    s  += __shfl_xor(s, 2, 64);  sq += __shfl_xor(sq, 2, 64);
    s  += __shfl_xor(s, 4, 64);  sq += __shfl_xor(sq, 4, 64);
    float mean = s * (1.f/192.f);
    float rstd = rsqrtf(sq * (1.f/192.f) - mean*mean + 1e-5f);
    const float4* g4 = (const float4*)(n1g + oct*24);
    const float4* b4 = (const float4*)(n1b + oct*24);
    #pragma unroll
    for (int j2 = 0; j2 < 3; j2++){
      float4 v0 = va[2*j2], v1 = va[2*j2+1];
      float4 g0 = g4[2*j2], g1 = g4[2*j2+1];
      float4 b0 = b4[2*j2], b1 = b4[2*j2+1];
      uint4 pk;
      pk.x = f2bf2((v0.x-mean)*rstd*g0.x+b0.x, (v0.y-mean)*rstd*g0.y+b0.y);
      pk.y = f2bf2((v0.z-mean)*rstd*g0.z+b0.z, (v0.w-mean)*rstd*g0.w+b0.w);
      pk.z = f2bf2((v1.x-mean)*rstd*g1.x+b1.x, (v1.y-mean)*rstd*g1.y+b1.y);
      pk.w = f2bf2((v1.z-mean)*rstd*g1.z+b1.z, (v1.w-mean)*rstd*g1.w+b1.w);
      int gk = oct*3 + j2;
      *(uint4*)&AsB[qrow*192 + ((gk ^ (qrow & 7)) << 3)] = pk;
    }
  }
  __syncthreads();                 // AsB + Rlds ready

  // ---- qkv GEMM: wave w computes output cols [w*48, w*48+48) ----
  // waves 0-3 -> Q, 4-7 -> K (into QKB); waves 8-11 -> V (into Vt)
  #pragma unroll
  for (int nf = 0; nf < 3; nf++){
    int cBase = w*48 + nf*16;
    bhalf8 wF[6];
    #pragma unroll
    for (int kk = 0; kk < 6; kk++)
      wF[kk] = *(const bhalf8*)&qkvWt[(size_t)(cBase + lr)*192 + kk*32 + (lg<<3)];
    float4 bv = *(const float4*)&qkv_b[cBase + (lg<<2)];
    #pragma unroll
    for (int i = 0; i < 4; i++){
      f32x4 a0 = (f32x4){0.f,0.f,0.f,0.f}, a1 = (f32x4){0.f,0.f,0.f,0.f};
      #pragma unroll
      for (int kk = 0; kk < 3; kk++){
        int row = i*16 + lr;
        bhalf8 t0 = *(const bhalf8*)&AsB[row*192 + (((2*kk*4     + lg) ^ (row & 7)) << 3)];
        bhalf8 t1 = *(const bhalf8*)&AsB[row*192 + ((((2*kk+1)*4 + lg) ^ (row & 7)) << 3)];
        a0 = __builtin_amdgcn_mfma_f32_16x16x32_bf16(wF[2*kk],   t0, a0, 0, 0, 0);
        a1 = __builtin_amdgcn_mfma_f32_16x16x32_bf16(wF[2*kk+1], t1, a1, 0, 0, 0);
      }
      float v0 = a0[0]+a1[0]+bv.x, v1 = a0[1]+a1[1]+bv.y;
      float v2 = a0[2]+a1[2]+bv.z, v3 = a0[3]+a1[3]+bv.w;
      int token = i*16 + lr;
      if (cBase < 384){            // Q|K: packed uint2 into swizzled QKB
        int gq = (cBase >> 3) + (lg >> 1);
        uint2 pk; pk.x = f2bf2(v0, v1); pk.y = f2bf2(v2, v3);
        *(uint2*)&QKB[token*384 + ((gq ^ (token & 7)) << 3) + ((lg & 1) << 2)] = pk;
      } else {                     // V: transposed scatter into Vt
        int d0 = cBase + (lg<<2) - 384;
        int hv = d0 >> 5;
        int db = d0 & 31;
        Vt[hv][(db+0)*64 + (token ^ (((db+0)&7)<<3))] = f2bf(v0);
        Vt[hv][(db+1)*64 + (token ^ (((db+1)&7)<<3))] = f2bf(v1);
        Vt[hv][(db+2)*64 + (token ^ (((db+2)&7)<<3))] = f2bf(v2);
        Vt[hv][(db+3)*64 + (token ^ (((db+3)&7)<<3))] = f2bf(v3);
      }
    }
  }
  __syncthreads();                 // QKB + Vt complete

  // ---- scores: wave (hd, half) = head hd, q-rows [half*32, half*32+32) ----
  int hd   = (w < 6) ? w : (w - 6);
  int half = (w < 6) ? 0 : 1;
  bhalf8 qf[2], kf[4];
  #pragma unroll
  for (int i = 0; i < 2; i++){
    int token = (half*2 + i)*16 + lr;
    int gq = hd*4 + lg;
    qf[i] = *(const bhalf8*)&QKB[token*384 + ((gq ^ (token & 7)) << 3)];
  }
  #pragma unroll
  for (int j = 0; j < 4; j++){
    int token = j*16 + lr;
    int gk = 24 + hd*4 + lg;
    kf[j] = *(const bhalf8*)&QKB[token*384 + ((gk ^ (token & 7)) << 3)];
  }
  f32x4 sc[2][4];
  f32x4 zero = (f32x4){0.f,0.f,0.f,0.f};
  #pragma unroll
  for (int i = 0; i < 2; i++)
    #pragma unroll
    for (int j = 0; j < 4; j++)
      sc[i][j] = __builtin_amdgcn_mfma_f32_16x16x32_bf16(qf[i], kf[j], zero, 0, 0, 0);
  __syncthreads();                 // all QKB reads done -> safe to overwrite with P

  // ---- softmax (+rel-pos bias +shift mask), P into QKB region ----
  u16* Plds = &QKB[0];
  int mwin = widx >> 5;            // faithful to reference reshape quirk
  int mh0 = (mwin >> 3) << 3, mw0 = (mwin & 7) << 3;
  #pragma unroll
  for (int i = 0; i < 2; i++){
    #pragma unroll
    for (int r = 0; r < 4; r++){
      int row = (half*2 + i)*16 + lg*4 + r;
      int ih = row >> 3, iw = row & 7;
      int ridr = region_id(mh0 + ih, mw0 + iw);
      float vals[4];
      #pragma unroll
      for (int j = 0; j < 4; j++){
        int col = j*16 + lr;
        int jh = col >> 3, jw = col & 7;
        float bias = Rlds[((ih-jh+7)*15 + (iw-jw+7))*6 + hd];
        int ridc = region_id(mh0 + jh, mw0 + jw);
        vals[j] = sc[i][j][r] * 0.17677669529663687f + bias + ((ridr==ridc) ? 0.f : -100.f);
      }
      float mx = fmaxf(fmaxf(vals[0],vals[1]), fmaxf(vals[2],vals[3]));
      #pragma unroll
      for (int d = 1; d < 16; d <<= 1) mx = fmaxf(mx, __shfl_xor(mx, d, 64));
      float sum = 0.f;
      #pragma unroll
      for (int j = 0; j < 4; j++){ vals[j] = __expf(vals[j]-mx); sum += vals[j]; }
      #pragma unroll
      for (int d = 1; d < 16; d <<= 1) sum += __shfl_xor(sum, d, 64);
      float inv = 1.f / sum;
      #pragma unroll
      for (int j = 0; j < 4; j++){
        int col = j*16 + lr;
        Plds[hd*4096 + row*64 + (col ^ ((row & 7) << 3))] = f2bf(vals[j]*inv);
      }
    }
  }

  // ---- PV: wave-local P rows + Vt[hd] ----
  f32x4 oa[2][2];
  #pragma unroll
  for (int i=0;i<2;i++)
    #pragma unroll
    for (int n=0;n<2;n++) oa[i][n] = zero;
  #pragma unroll
  for (int kb = 0; kb < 2; kb++){
    bhalf8 pf[2], vf[2];
    int k = (kb<<5) + (lg<<3);
    #pragma unroll
    for (int i = 0; i < 2; i++){
      int row = (half*2 + i)*16 + lr;
      pf[i] = *(const bhalf8*)&Plds[hd*4096 + row*64 + (k ^ ((row&7)<<3))];
    }
    #pragma unroll
    for (int n = 0; n < 2; n++){
      int d = n*16 + lr;
      vf[n] = *(const bhalf8*)&Vt[hd][d*64 + (k ^ ((d&7)<<3))];
    }
    #pragma unroll
    for (int i=0;i<2;i++)
      #pragma unroll
      for (int n=0;n<2;n++)
        oa[i][n] = __builtin_amdgcn_mfma_f32_16x16x32_bf16(pf[i], vf[n], oa[i][n], 0, 0, 0);
  }

  // ---- ctx -> Clds (aliases AsB; AsB dead since qkv barrier) ----
  u16* Clds = &AsB[0];
  #pragma unroll
  for (int i=0;i<2;i++)
    #pragma unroll
    for (int n=0;n<2;n++)
      #pragma unroll
      for (int r=0;r<4;r++){
        int row = (half*2 + i)*16 + lg*4 + r;
        int col = hd*32 + n*16 + lr;
        Clds[row*192 + (((col>>3) ^ (row&7)) << 3) + (col & 7)] = f2bf(oa[i][n][r]);
      }
  __syncthreads();                 // ctx complete

  // ---- proj (64x192 @ 192x192) + residual scatter; wave does rows [half*32,+32), cols [hd*32,+32) ----
  f32x4 pacc[2][2];
  #pragma unroll
  for (int i=0;i<2;i++)
    #pragma unroll
    for (int n=0;n<2;n++) pacc[i][n] = zero;
  #pragma unroll
  for (int kk = 0; kk < 6; kk++){
    bhalf8 af[2], bf[2];
    #pragma unroll
    for (int i = 0; i < 2; i++){
      int row = half*32 + i*16 + lr;
      af[i] = *(const bhalf8*)&Clds[row*192 + (((kk*4 + lg) ^ (row & 7)) << 3)];
    }
    #pragma unroll
    for (int n = 0; n < 2; n++){
      int col = hd*32 + n*16 + lr;
      bf[n] = *(const bhalf8*)&projWt[(size_t)col*192 + kk*32 + (lg<<3)];
    }
    #pragma unroll
    for (int i=0;i<2;i++)
      #pragma unroll
      for (int n=0;n<2;n++)
        pacc[i][n] = __builtin_amdgcn_mfma_f32_16x16x32_bf16(af[i], bf[n], pacc[i][n], 0, 0, 0);
  }
  #pragma unroll
  for (int i=0;i<2;i++)
    #pragma unroll
    for (int n=0;n<2;n++){
      int col = hd*32 + n*16 + lr;
      float bv = proj_b[col];
      #pragma unroll
      for (int r=0;r<4;r++){
        int rowl = half*32 + i*16 + lg*4 + r;
        int g = tok2glob(widx*64 + rowl);
        size_t o = (size_t)g*192 + col;
        out[o] = x[o] + bv + pacc[i][n][r];
      }
    }
}

// =================== mlp_fused: 64 tokens / block, 256 threads, 6 passes of 128 cols ===================
__global__ __launch_bounds__(256, 4) void mlp_fused_kernel(
    const float* __restrict__ X, const float* __restrict__ n2g, const float* __restrict__ n2b,
    const u16* __restrict__ fc1Wt, const float* __restrict__ fc1_b,
    const u16* __restrict__ fc2Wt, const float* __restrict__ fc2_b,
    float* out){
  __shared__ u16 As[64*192];       // 24 KB
  __shared__ u16 Hb[64*128];       // 16 KB: one 128-col slice of H1
  int tid = threadIdx.x;
  int mBase = blockIdx.x << 6;

  { // LN2: 4 threads/row, 48 f32 each
    int qrow = tid >> 2, quarter = tid & 3;
    const float4* xr = (const float4*)(X + (size_t)(mBase + qrow)*192 + quarter*48);
    float4 va[12];
    float s = 0.f, sq = 0.f;
    #pragma unroll
    for (int j = 0; j < 12; j++){
      va[j] = xr[j];
      s  += va[j].x + va[j].y + va[j].z + va[j].w;
      sq += va[j].x*va[j].x + va[j].y*va[j].y + va[j].z*va[j].z + va[j].w*va[j].w;
    }
    s  += __shfl_xor(s, 1, 64);  sq += __shfl_xor(sq, 1, 64);
    s  += __shfl_xor(s, 2, 64);  sq += __shfl_xor(sq, 2, 64);
    float mean = s * (1.f/192.f);
    float rstd = rsqrtf(sq * (1.f/192.f) - mean*mean + 1e-5f);
    const float4* g4 = (const float4*)(n2g + quarter*48);
    const float4* b4 = (const float4*)(n2b + quarter*48);
    #pragma unroll
    for (int j2 = 0; j2 < 6; j2++){
      float4 v0 = va[2*j2], v1 = va[2*j2+1];
      float4 g0 = g4[2*j2], g1 = g4[2*j2+1];
      float4 b0 = b4[2*j2], b1 = b4[2*j2+1];
      uint4 pk;
      pk.x = f2bf2((v0.x-mean)*rstd*g0.x+b0.x, (v0.y-mean)*rstd*g0.y+b0.y);
      pk.y = f2bf2((v0.z-mean)*rstd*g0.z+b0.z, (v0.w-mean)*rstd*g0.w+b0.w);
      pk.z = f2bf2((v1.x-mean)*rstd*g1.x+b1.x, (v1.y-mean)*rstd*g1.y+b1.y);
      pk.w = f2bf2((v1.z-mean)*rstd*g1.z+b1.z, (v1.w-mean)*rstd*g1.w+b1.w);
      int gk = quarter*6 + j2;
      *(uint4*)&As[qrow*192 + ((gk ^ (qrow & 7)) << 3)] = pk;
    }
  }
  __syncthreads();

  int lane = tid & 63, w = tid >> 6;
  int lr = lane & 15, lg = lane >> 4;
  f32x4 acc2[4][3];
  #pragma unroll
  for (int i=0;i<4;i++)
    #pragma unroll
    for (int n=0;n<3;n++) acc2[i][n] = (f32x4){0.f,0.f,0.f,0.f};

  #pragma unroll
  for (int p = 0; p < 6; p++){
    // ---- fc1: wave w computes cols [p*128 + w*32, +32) ----
    #pragma unroll
    for (int nf = 0; nf < 2; nf++){
      int cBase = w*32 + nf*16;          // col within the 128-slice
      int gcol = p*128 + cBase;
      bhalf8 wF[6];
      #pragma unroll
      for (int kk = 0; kk < 6; kk++)
        wF[kk] = *(const bhalf8*)&fc1Wt[(size_t)(gcol + lr)*192 + kk*32 + (lg<<3)];
      float4 bv = *(const float4*)&fc1_b[gcol + (lg<<2)];
      #pragma unroll
      for (int i = 0; i < 4; i++){
        f32x4 a0 = (f32x4){0.f,0.f,0.f,0.f}, a1 = (f32x4){0.f,0.f,0.f,0.f};
        #pragma unroll
        for (int kk = 0; kk < 3; kk++){
          int row = i*16 + lr;
          bhalf8 t0 = *(const bhalf8*)&As[row*192 + (((2*kk*4     + lg) ^ (row & 7)) << 3)];
          bhalf8 t1 = *(const bhalf8*)&As[row*192 + ((((2*kk+1)*4 + lg) ^ (row & 7)) << 3)];
          a0 = __builtin_amdgcn_mfma_f32_16x16x32_bf16(wF[2*kk],   t0, a0, 0, 0, 0);
          a1 = __builtin_amdgcn_mfma_f32_16x16x32_bf16(wF[2*kk+1], t1, a1, 0, 0, 0);
        }
        float v0 = fast_gelu(a0[0]+a1[0]+bv.x);
        float v1 = fast_gelu(a0[1]+a1[1]+bv.y);
        float v2 = fast_gelu(a0[2]+a1[2]+bv.z);
        float v3 = fast_gelu(a0[3]+a1[3]+bv.w);
        int token = i*16 + lr;
        int g0 = 4*w + 2*nf + (lg >> 1);     // granule of col cBase+lg*4 within 128-slice
        uint2 pk; pk.x = f2bf2(v0, v1); pk.y = f2bf2(v2, v3);
        *(uint2*)&Hb[token*128 + ((g0 ^ (token & 7)) << 3) + ((lg & 1) << 2)] = pk;
      }
    }
    __syncthreads();                     // Hb ready

    // ---- fc2 partial accumulate over this 128-col K slice; wave w -> ch [w*48,+48) ----
    #pragma unroll
    for (int kb = 0; kb < 4; kb++){
      bhalf8 hF[4];
      #pragma unroll
      for (int i2 = 0; i2 < 4; i2++){
        int token = i2*16 + lr;
        int g = kb*4 + lg;
        hF[i2] = *(const bhalf8*)&Hb[token*128 + ((g ^ (token & 7)) << 3)];
      }
      bhalf8 w2F[3];
      #pragma unroll
      for (int nf = 0; nf < 3; nf++){
        int ch = w*48 + nf*16 + lr;
        w2F[nf] = *(const bhalf8*)&fc2Wt[(size_t)ch*768 + p*128 + kb*32 + (lg<<3)];
      }
      #pragma unroll
      for (int i2 = 0; i2 < 4; i2++)
        #pragma unroll
        for (int nf = 0; nf < 3; nf++)
          acc2[i2][nf] = __builtin_amdgcn_mfma_f32_16x16x32_bf16(w2F[nf], hF[i2], acc2[i2][nf], 0, 0, 0);
    }
    __syncthreads();                     // fc2 reads done before next pass overwrites Hb
  }

  // ---- epilogue: residual RMW, float4 ----
  #pragma unroll
  for (int i2 = 0; i2 < 4; i2++)
    #pragma unroll
    for (int nf = 0; nf < 3; nf++){
      int col = w*48 + nf*16 + (lg<<2);
      float4 bv = *(const float4*)&fc2_b[col];
      int row = mBase + i2*16 + lr;
      float4* op = (float4*)&out[(size_t)row*192 + col];
      float4 o = *op;
      o.x += bv.x + acc2[i2][nf][0];
      o.y += bv.y + acc2[i2][nf][1];
      o.z += bv.z + acc2[i2][nf][2];
      o.w += bv.w + acc2[i2][nf][3];
      *op = o;
    }
}

extern "C" void kernel_launch(void* const* d_in, const int* in_sizes, int n_in,
                              void* d_out, int out_size, void* d_ws, size_t ws_size,
                              hipStream_t stream){
  const float* x      = (const float*)d_in[0];
  const float* n1g    = (const float*)d_in[1];
  const float* n1b    = (const float*)d_in[2];
  const float* qkv_w  = (const float*)d_in[3];
  const float* qkv_b  = (const float*)d_in[4];
  const float* proj_w = (const float*)d_in[5];
  const float* proj_b = (const float*)d_in[6];
  const float* rpb    = (const float*)d_in[7];
  const float* n2g    = (const float*)d_in[8];
  const float* n2b    = (const float*)d_in[9];
  const float* fc1_w  = (const float*)d_in[10];
  const float* fc1_b  = (const float*)d_in[11];
  const float* fc2_w  = (const float*)d_in[12];
  const float* fc2_b  = (const float*)d_in[13];
  float* out = (float*)d_out;

  u16* qkvWt  = (u16*)d_ws;
  u16* projWt = qkvWt + 576*192;
  u16* fc1Wt  = projWt + 192*192;
  u16* fc2Wt  = fc1Wt + 768*192;

  transcast_kernel<<<dim3((192*576+255)/256),256,0,stream>>>(qkv_w, qkvWt, 192, 576);
  transcast_kernel<<<dim3((192*192+255)/256),256,0,stream>>>(proj_w, projWt, 192, 192);
  transcast_kernel<<<dim3((192*768+255)/256),256,0,stream>>>(fc1_w, fc1Wt, 192, 768);
  transcast_kernel<<<dim3((768*192+255)/256),256,0,stream>>>(fc2_w, fc2Wt, 768, 192);

  // LN1 + qkv + attention + proj + residual -> out (xmid)
  attn_fused_kernel<<<dim3(2048),768,0,stream>>>(x, n1g, n1b, qkvWt, qkv_b,
                                                 projWt, proj_b, out, rpb);
  // LN2 + fc1 + GELU + fc2 + residual (in-place on out)
  mlp_fused_kernel<<<dim3(2048),256,0,stream>>>(out, n2g, n2b, fc1Wt, fc1_b,
                                                fc2Wt, fc2_b, out);
}

// Round 7
// 491.926 us; speedup vs baseline: 1.3384x; 1.0283x over previous
//
#include <hip/hip_runtime.h>
#include <hip/hip_bf16.h>

// Swin block, MI355X. v7: MLP un-fused into ln2 / fc1 / fc2 with proper reuse:
//  fc1: 256-token blocks, reg-resident A, LDS-dbuf weights, 1 barrier/tile.
//  fc2: 256-token blocks, H+W LDS-dbuf (112KB), 1 barrier/pass, H1 read once.
// attn_fused kept from v6. B=32 H=W=64 C=192 WS=8 SS=4 NH=6 Dh=32; T=131072.

#define DI __device__ __forceinline__

typedef __attribute__((ext_vector_type(8))) short bhalf8;   // 8 bf16 (4 VGPR)
typedef __attribute__((ext_vector_type(4))) float f32x4;
typedef unsigned short u16;
typedef unsigned int   u32;

DI u16 f2bf(float f){                       // RNE f32->bf16
  union { float f; u32 u; } v; v.f = f;
  u32 r = v.u + 0x7FFFu + ((v.u >> 16) & 1u);
  return (u16)(r >> 16);
}
DI u32 f2bf2(float a, float b){ return (u32)f2bf(a) | ((u32)f2bf(b) << 16); }

// gelu(x)=0.5x(1+erf(x/sqrt2)); erf via Abramowitz-Stegun 7.1.26 (|err|<1.5e-7)
DI float fast_gelu(float x){
  float ax = fabsf(x) * 0.70710678118654752f;
  float t = 1.0f / fmaf(0.3275911f, ax, 1.0f);
  float poly = t*(0.254829592f + t*(-0.284496736f + t*(1.421413741f +
               t*(-1.453152027f + t*1.061405429f))));
  float erfv = 1.0f - poly * __expf(-ax*ax);
  erfv = (x < 0.f) ? -erfv : erfv;
  return 0.5f * x * (1.0f + erfv);
}

// window-token index t -> global token g (shift+partition map; gather & scatter identical)
DI int tok2glob(int t){
  int n = t & 63, widx = t >> 6;
  int b = widx >> 6, wi = widx & 63;
  int hh = ((wi >> 3) << 3) + (n >> 3);
  int ww = ((wi & 7) << 3) + (n & 7);
  int hs = (hh + 4) & 63, wsv = (ww + 4) & 63;
  return (b << 12) + (hs << 6) + wsv;
}

DI int region_id(int hpos, int wpos){
  int rh = (hpos < 56) ? 0 : ((hpos < 60) ? 1 : 2);
  int rw = (wpos < 56) ? 0 : ((wpos < 60) ? 1 : 2);
  return rh*3 + rw;
}

// ------------- weight prep: W(K,N) fp32 -> Wt(N,K) bf16 -------------
__global__ void transcast_kernel(const float* __restrict__ W, u16* __restrict__ Wt, int K, int N){
  int idx = blockIdx.x * 256 + threadIdx.x;
  if (idx < K*N){
    int n = idx / K, k = idx - n*K;
    Wt[idx] = f2bf(W[(size_t)k * N + n]);
  }
}

// =================== attn_fused: 1 block / window, 768 threads (12 waves) ===================
__global__ __launch_bounds__(768, 3) void attn_fused_kernel(
    const float* __restrict__ x, const float* __restrict__ n1g, const float* __restrict__ n1b,
    const u16* __restrict__ qkvWt, const float* __restrict__ qkv_b,
    const u16* __restrict__ projWt, const float* __restrict__ proj_b,
    float* __restrict__ out, const float* __restrict__ rpb){
  __shared__ u16 AsB[64*192];      // 24 KB: LN'd tokens; later aliased as Clds
  __shared__ u16 QKB[64*384];      // 48 KB: Q|K tiles; later aliased as P (6 x 64x64)
  __shared__ u16 Vt[6][32*64];     // 24 KB: V^T per head, XOR-swizzled
  __shared__ float Rlds[225*6];
  int widx = blockIdx.x;
  int tid  = threadIdx.x;
  int w = tid >> 6, lane = tid & 63, lr = lane & 15, lg = lane >> 4;

  if (w >= 8){                     // waves 8-11: stage rel-pos bias
    for (int i = tid - 512; i < 225*6; i += 256) Rlds[i] = rpb[i];
  } else {                         // waves 0-7: LN1, 8 threads/row
    int qrow = tid >> 3, oct = tid & 7;
    int g = tok2glob(widx*64 + qrow);
    const float4* xr = (const float4*)(x + (size_t)g*192 + oct*24);
    float4 va[6];
    float s = 0.f, sq = 0.f;
    #pragma unroll
    for (int j = 0; j < 6; j++){
      va[j] = xr[j];
      s  += va[j].x + va[j].y + va[j].z + va[j].w;
      sq += va[j].x*va[j].x + va[j].y*va[j].y + va[j].z*va[j].z + va[j].w*va[j].w;
    }
    s  += __shfl_xor(s, 1, 64);  sq += __shfl_xor(sq, 1, 64);
    s  += __shfl_xor(s, 2, 64);  sq += __shfl_xor(sq, 2, 64);
    s  += __shfl_xor(s, 4, 64);  sq += __shfl_xor(sq, 4, 64);
    float mean = s * (1.f/192.f);
    float rstd = rsqrtf(sq * (1.f/192.f) - mean*mean + 1e-5f);
    const float4* g4 = (const float4*)(n1g + oct*24);
    const float4* b4 = (const float4*)(n1b + oct*24);
    #pragma unroll
    for (int j2 = 0; j2 < 3; j2++){
      float4 v0 = va[2*j2], v1 = va[2*j2+1];
      float4 g0 = g4[2*j2], g1 = g4[2*j2+1];
      float4 b0 = b4[2*j2], b1 = b4[2*j2+1];
      uint4 pk;
      pk.x = f2bf2((v0.x-mean)*rstd*g0.x+b0.x, (v0.y-mean)*rstd*g0.y+b0.y);
      pk.y = f2bf2((v0.z-mean)*rstd*g0.z+b0.z, (v0.w-mean)*rstd*g0.w+b0.w);
      pk.z = f2bf2((v1.x-mean)*rstd*g1.x+b1.x, (v1.y-mean)*rstd*g1.y+b1.y);
      pk.w = f2bf2((v1.z-mean)*rstd*g1.z+b1.z, (v1.w-mean)*rstd*g1.w+b1.w);
      int gk = oct*3 + j2;
      *(uint4*)&AsB[qrow*192 + ((gk ^ (qrow & 7)) << 3)] = pk;
    }
  }
  __syncthreads();                 // AsB + Rlds ready

  // ---- qkv GEMM: wave w computes output cols [w*48, w*48+48) ----
  #pragma unroll
  for (int nf = 0; nf < 3; nf++){
    int cBase = w*48 + nf*16;
    bhalf8 wF[6];
    #pragma unroll
    for (int kk = 0; kk < 6; kk++)
      wF[kk] = *(const bhalf8*)&qkvWt[(size_t)(cBase + lr)*192 + kk*32 + (lg<<3)];
    float4 bv = *(const float4*)&qkv_b[cBase + (lg<<2)];
    #pragma unroll
    for (int i = 0; i < 4; i++){
      f32x4 a0 = (f32x4){0.f,0.f,0.f,0.f}, a1 = (f32x4){0.f,0.f,0.f,0.f};
      #pragma unroll
      for (int kk = 0; kk < 3; kk++){
        int row = i*16 + lr;
        bhalf8 t0 = *(const bhalf8*)&AsB[row*192 + (((2*kk*4     + lg) ^ (row & 7)) << 3)];
        bhalf8 t1 = *(const bhalf8*)&AsB[row*192 + ((((2*kk+1)*4 + lg) ^ (row & 7)) << 3)];
        a0 = __builtin_amdgcn_mfma_f32_16x16x32_bf16(wF[2*kk],   t0, a0, 0, 0, 0);
        a1 = __builtin_amdgcn_mfma_f32_16x16x32_bf16(wF[2*kk+1], t1, a1, 0, 0, 0);
      }
      float v0 = a0[0]+a1[0]+bv.x, v1 = a0[1]+a1[1]+bv.y;
      float v2 = a0[2]+a1[2]+bv.z, v3 = a0[3]+a1[3]+bv.w;
      int token = i*16 + lr;
      if (cBase < 384){            // Q|K: packed uint2 into swizzled QKB
        int gq = (cBase >> 3) + (lg >> 1);
        uint2 pk; pk.x = f2bf2(v0, v1); pk.y = f2bf2(v2, v3);
        *(uint2*)&QKB[token*384 + ((gq ^ (token & 7)) << 3) + ((lg & 1) << 2)] = pk;
      } else {                     // V: transposed scatter into Vt
        int d0 = cBase + (lg<<2) - 384;
        int hv = d0 >> 5;
        int db = d0 & 31;
        Vt[hv][(db+0)*64 + (token ^ (((db+0)&7)<<3))] = f2bf(v0);
        Vt[hv][(db+1)*64 + (token ^ (((db+1)&7)<<3))] = f2bf(v1);
        Vt[hv][(db+2)*64 + (token ^ (((db+2)&7)<<3))] = f2bf(v2);
        Vt[hv][(db+3)*64 + (token ^ (((db+3)&7)<<3))] = f2bf(v3);
      }
    }
  }
  __syncthreads();                 // QKB + Vt complete

  // ---- scores: wave (hd, half) = head hd, q-rows [half*32, half*32+32) ----
  int hd   = (w < 6) ? w : (w - 6);
  int half = (w < 6) ? 0 : 1;
  bhalf8 qf[2], kf[4];
  #pragma unroll
  for (int i = 0; i < 2; i++){
    int token = (half*2 + i)*16 + lr;
    int gq = hd*4 + lg;
    qf[i] = *(const bhalf8*)&QKB[token*384 + ((gq ^ (token & 7)) << 3)];
  }
  #pragma unroll
  for (int j = 0; j < 4; j++){
    int token = j*16 + lr;
    int gk = 24 + hd*4 + lg;
    kf[j] = *(const bhalf8*)&QKB[token*384 + ((gk ^ (token & 7)) << 3)];
  }
  f32x4 sc[2][4];
  f32x4 zero = (f32x4){0.f,0.f,0.f,0.f};
  #pragma unroll
  for (int i = 0; i < 2; i++)
    #pragma unroll
    for (int j = 0; j < 4; j++)
      sc[i][j] = __builtin_amdgcn_mfma_f32_16x16x32_bf16(qf[i], kf[j], zero, 0, 0, 0);
  __syncthreads();                 // all QKB reads done -> safe to overwrite with P

  // ---- softmax (+rel-pos bias +shift mask), P into QKB region ----
  u16* Plds = &QKB[0];
  int mwin = widx >> 5;            // faithful to reference reshape quirk
  int mh0 = (mwin >> 3) << 3, mw0 = (mwin & 7) << 3;
  #pragma unroll
  for (int i = 0; i < 2; i++){
    #pragma unroll
    for (int r = 0; r < 4; r++){
      int row = (half*2 + i)*16 + lg*4 + r;
      int ih = row >> 3, iw = row & 7;
      int ridr = region_id(mh0 + ih, mw0 + iw);
      float vals[4];
      #pragma unroll
      for (int j = 0; j < 4; j++){
        int col = j*16 + lr;
        int jh = col >> 3, jw = col & 7;
        float bias = Rlds[((ih-jh+7)*15 + (iw-jw+7))*6 + hd];
        int ridc = region_id(mh0 + jh, mw0 + jw);
        vals[j] = sc[i][j][r] * 0.17677669529663687f + bias + ((ridr==ridc) ? 0.f : -100.f);
      }
      float mx = fmaxf(fmaxf(vals[0],vals[1]), fmaxf(vals[2],vals[3]));
      #pragma unroll
      for (int d = 1; d < 16; d <<= 1) mx = fmaxf(mx, __shfl_xor(mx, d, 64));
      float sum = 0.f;
      #pragma unroll
      for (int j = 0; j < 4; j++){ vals[j] = __expf(vals[j]-mx); sum += vals[j]; }
      #pragma unroll
      for (int d = 1; d < 16; d <<= 1) sum += __shfl_xor(sum, d, 64);
      float inv = 1.f / sum;
      #pragma unroll
      for (int j = 0; j < 4; j++){
        int col = j*16 + lr;
        Plds[hd*4096 + row*64 + (col ^ ((row & 7) << 3))] = f2bf(vals[j]*inv);
      }
    }
  }

  // ---- PV: wave-local P rows + Vt[hd] ----
  f32x4 oa[2][2];
  #pragma unroll
  for (int i=0;i<2;i++)
    #pragma unroll
    for (int n=0;n<2;n++) oa[i][n] = zero;
  #pragma unroll
  for (int kb = 0; kb < 2; kb++){
    bhalf8 pf[2], vf[2];
    int k = (kb<<5) + (lg<<3);
    #pragma unroll
    for (int i = 0; i < 2; i++){
      int row = (half*2 + i)*16 + lr;
      pf[i] = *(const bhalf8*)&Plds[hd*4096 + row*64 + (k ^ ((row&7)<<3))];
    }
    #pragma unroll
    for (int n = 0; n < 2; n++){
      int d = n*16 + lr;
      vf[n] = *(const bhalf8*)&Vt[hd][d*64 + (k ^ ((d&7)<<3))];
    }
    #pragma unroll
    for (int i=0;i<2;i++)
      #pragma unroll
      for (int n=0;n<2;n++)
        oa[i][n] = __builtin_amdgcn_mfma_f32_16x16x32_bf16(pf[i], vf[n], oa[i][n], 0, 0, 0);
  }

  // ---- ctx -> Clds (aliases AsB; AsB dead since qkv barrier) ----
  u16* Clds = &AsB[0];
  #pragma unroll
  for (int i=0;i<2;i++)
    #pragma unroll
    for (int n=0;n<2;n++)
      #pragma unroll
      for (int r=0;r<4;r++){
        int row = (half*2 + i)*16 + lg*4 + r;
        int col = hd*32 + n*16 + lr;
        Clds[row*192 + (((col>>3) ^ (row&7)) << 3) + (col & 7)] = f2bf(oa[i][n][r]);
      }
  __syncthreads();                 // ctx complete

  // ---- proj + residual scatter; wave does rows [half*32,+32), cols [hd*32,+32) ----
  f32x4 pacc[2][2];
  #pragma unroll
  for (int i=0;i<2;i++)
    #pragma unroll
    for (int n=0;n<2;n++) pacc[i][n] = zero;
  #pragma unroll
  for (int kk = 0; kk < 6; kk++){
    bhalf8 af[2], bf[2];
    #pragma unroll
    for (int i = 0; i < 2; i++){
      int row = half*32 + i*16 + lr;
      af[i] = *(const bhalf8*)&Clds[row*192 + (((kk*4 + lg) ^ (row & 7)) << 3)];
    }
    #pragma unroll
    for (int n = 0; n < 2; n++){
      int col = hd*32 + n*16 + lr;
      bf[n] = *(const bhalf8*)&projWt[(size_t)col*192 + kk*32 + (lg<<3)];
    }
    #pragma unroll
    for (int i=0;i<2;i++)
      #pragma unroll
      for (int n=0;n<2;n++)
        pacc[i][n] = __builtin_amdgcn_mfma_f32_16x16x32_bf16(af[i], bf[n], pacc[i][n], 0, 0, 0);
  }
  #pragma unroll
  for (int i=0;i<2;i++)
    #pragma unroll
    for (int n=0;n<2;n++){
      int col = hd*32 + n*16 + lr;
      float bv = proj_b[col];
      #pragma unroll
      for (int r=0;r<4;r++){
        int rowl = half*32 + i*16 + lg*4 + r;
        int g = tok2glob(widx*64 + rowl);
        size_t o = (size_t)g*192 + col;
        out[o] = x[o] + bv + pacc[i][n][r];
      }
    }
}

// =================== ln2: out(fp32) -> A2(bf16), 64 rows/block ===================
__global__ __launch_bounds__(256) void ln2_kernel(const float* __restrict__ X,
    const float* __restrict__ gam, const float* __restrict__ bet, u16* __restrict__ A2){
  int tid = threadIdx.x;
  int row = (blockIdx.x << 6) + (tid >> 2), quarter = tid & 3;
  const float4* xr = (const float4*)(X + (size_t)row*192 + quarter*48);
  float4 va[12];
  float s = 0.f, sq = 0.f;
  #pragma unroll
  for (int j = 0; j < 12; j++){
    va[j] = xr[j];
    s  += va[j].x + va[j].y + va[j].z + va[j].w;
    sq += va[j].x*va[j].x + va[j].y*va[j].y + va[j].z*va[j].z + va[j].w*va[j].w;
  }
  s  += __shfl_xor(s, 1, 64);  sq += __shfl_xor(sq, 1, 64);
  s  += __shfl_xor(s, 2, 64);  sq += __shfl_xor(sq, 2, 64);
  float mean = s * (1.f/192.f);
  float rstd = rsqrtf(sq * (1.f/192.f) - mean*mean + 1e-5f);
  const float4* g4 = (const float4*)(gam + quarter*48);
  const float4* b4 = (const float4*)(bet + quarter*48);
  #pragma unroll
  for (int j2 = 0; j2 < 6; j2++){
    float4 v0 = va[2*j2], v1 = va[2*j2+1];
    float4 g0 = g4[2*j2], g1 = g4[2*j2+1];
    float4 b0 = b4[2*j2], b1 = b4[2*j2+1];
    uint4 pk;
    pk.x = f2bf2((v0.x-mean)*rstd*g0.x+b0.x, (v0.y-mean)*rstd*g0.y+b0.y);
    pk.y = f2bf2((v0.z-mean)*rstd*g0.z+b0.z, (v0.w-mean)*rstd*g0.w+b0.w);
    pk.z = f2bf2((v1.x-mean)*rstd*g1.x+b1.x, (v1.y-mean)*rstd*g1.y+b1.y);
    pk.w = f2bf2((v1.z-mean)*rstd*g1.z+b1.z, (v1.w-mean)*rstd*g1.w+b1.w);
    *(uint4*)&A2[(size_t)row*192 + quarter*48 + j2*8] = pk;
  }
}

// =================== fc1: 256 tokens/block, 4 waves, W LDS-dbuf, gelu ===================
__global__ __launch_bounds__(256, 3) void fc1_kernel(const u16* __restrict__ A2,
    const u16* __restrict__ Bt, const float* __restrict__ bias, u16* __restrict__ H1){
  __shared__ u16 Wl[2][64*192];               // 24 KB each, granule-swizzled
  int tid = threadIdx.x;
  int mBase = blockIdx.x << 8;                // 256 tokens
  int lane = tid & 63, w = tid >> 6;
  int lr = lane & 15, lg = lane >> 4;
  int tokBase = mBase + (w << 6);             // wave's 64 tokens

  // hoist A fragments: 64 tokens x K=192 in regs (24 bhalf8)
  bhalf8 tF[4][6];
  #pragma unroll
  for (int i = 0; i < 4; i++)
    #pragma unroll
    for (int kk = 0; kk < 6; kk++)
      tF[i][kk] = *(const bhalf8*)&A2[(size_t)(tokBase + i*16 + lr)*192 + kk*32 + (lg<<3)];

  // stage: thread t -> col = t>>2, granules (t&3)*6 + j (96B contiguous per thread)
  int scol = tid >> 2, sg0 = (tid & 3) * 6;
  const u16* srcBase = Bt + (size_t)scol*192;
  #define STAGE_FC1(nt, buf) { \
    const u16* sp = srcBase + (size_t)(nt)*64*192 + sg0*8; \
    _Pragma("unroll") \
    for (int j = 0; j < 6; j++){ \
      uint4 v = *(const uint4*)(sp + j*8); \
      *(uint4*)&Wl[buf][scol*192 + (((sg0 + j) ^ (scol & 7)) << 3)] = v; \
    } }

  STAGE_FC1(0, 0)
  for (int nt = 0; nt < 12; nt++){
    __syncthreads();
    if (nt < 11) STAGE_FC1(nt + 1, (nt + 1) & 1)
    int buf = nt & 1;
    #pragma unroll
    for (int cf = 0; cf < 4; cf++){
      bhalf8 wF[6];
      int col = cf*16 + lr;
      #pragma unroll
      for (int kk = 0; kk < 6; kk++)
        wF[kk] = *(const bhalf8*)&Wl[buf][col*192 + (((kk*4 + lg) ^ (col & 7)) << 3)];
      int gcol = (nt << 6) + cf*16;
      float4 bv = *(const float4*)&bias[gcol + (lg<<2)];
      #pragma unroll
      for (int i = 0; i < 4; i++){
        f32x4 a0 = (f32x4){0.f,0.f,0.f,0.f}, a1 = (f32x4){0.f,0.f,0.f,0.f};
        #pragma unroll
        for (int kk = 0; kk < 3; kk++){
          a0 = __builtin_amdgcn_mfma_f32_16x16x32_bf16(wF[2*kk],   tF[i][2*kk],   a0, 0, 0, 0);
          a1 = __builtin_amdgcn_mfma_f32_16x16x32_bf16(wF[2*kk+1], tF[i][2*kk+1], a1, 0, 0, 0);
        }
        float v0 = fast_gelu(a0[0]+a1[0]+bv.x);
        float v1 = fast_gelu(a0[1]+a1[1]+bv.y);
        float v2 = fast_gelu(a0[2]+a1[2]+bv.z);
        float v3 = fast_gelu(a0[3]+a1[3]+bv.w);
        uint2 pk; pk.x = f2bf2(v0, v1); pk.y = f2bf2(v2, v3);
        *(uint2*)&H1[(size_t)(tokBase + i*16 + lr)*768 + gcol + (lg<<2)] = pk;
      }
    }
  }
  #undef STAGE_FC1
}

// =================== fc2: 256 tokens/block, 8 waves, H+W LDS-dbuf, residual RMW ===================
__global__ __launch_bounds__(512, 2) void fc2_kernel(const u16* __restrict__ H1,
    const u16* __restrict__ Bt, const float* __restrict__ bias, float* out){
  __shared__ u16 Hl[2][256*64];               // 32 KB each
  __shared__ u16 Wl[2][192*64];               // 24 KB each
  int tid = threadIdx.x;
  int mBase = blockIdx.x << 8;                // 256 tokens
  int lane = tid & 63, w = tid >> 6;
  int lr = lane & 15, lg = lane >> 4;
  int mq = w >> 1, nh = w & 1;                // wave = 64 tokens x 96 cols

  // stage thread mapping (no divisions): H: tok = j*64 + (tid>>3); W: col = j*64 + (tid>>3)
  int srow = tid >> 3, sgk = tid & 7;
  #define STAGE_FC2(p, buf) { \
    _Pragma("unroll") \
    for (int j = 0; j < 4; j++){ \
      int tok = j*64 + srow; \
      uint4 v = *(const uint4*)&H1[(size_t)(mBase + tok)*768 + (p)*64 + sgk*8]; \
      *(uint4*)&Hl[buf][tok*64 + ((sgk ^ (tok & 7)) << 3)] = v; \
    } \
    _Pragma("unroll") \
    for (int j = 0; j < 3; j++){ \
      int col = j*64 + srow; \
      uint4 v = *(const uint4*)&Bt[(size_t)col*768 + (p)*64 + sgk*8]; \
      *(uint4*)&Wl[buf][col*64 + ((sgk ^ (col & 7)) << 3)] = v; \
    } }

  f32x4 acc[4][6];
  #pragma unroll
  for (int i = 0; i < 4; i++)
    #pragma unroll
    for (int cf = 0; cf < 6; cf++) acc[i][cf] = (f32x4){0.f,0.f,0.f,0.f};

  STAGE_FC2(0, 0)
  for (int p = 0; p < 12; p++){
    __syncthreads();
    if (p < 11) STAGE_FC2(p + 1, (p + 1) & 1)
    int buf = p & 1;
    #pragma unroll
    for (int kk = 0; kk < 2; kk++){
      bhalf8 hF[4], wv[6];
      #pragma unroll
      for (int i = 0; i < 4; i++){
        int tok = mq*64 + i*16 + lr;
        hF[i] = *(const bhalf8*)&Hl[buf][tok*64 + (((kk*4 + lg) ^ (tok & 7)) << 3)];
      }
      #pragma unroll
      for (int cf = 0; cf < 6; cf++){
        int col = nh*96 + cf*16 + lr;
        wv[cf] = *(const bhalf8*)&Wl[buf][col*64 + (((kk*4 + lg) ^ (col & 7)) << 3)];
      }
      #pragma unroll
      for (int i = 0; i < 4; i++)
        #pragma unroll
        for (int cf = 0; cf < 6; cf++)
          acc[i][cf] = __builtin_amdgcn_mfma_f32_16x16x32_bf16(wv[cf], hF[i], acc[i][cf], 0, 0, 0);
    }
  }
  #undef STAGE_FC2

  // epilogue: residual RMW float4; token = mq*64+i*16+lr, cols = nh*96+cf*16+lg*4
  #pragma unroll
  for (int i = 0; i < 4; i++)
    #pragma unroll
    for (int cf = 0; cf < 6; cf++){
      int col = nh*96 + cf*16 + (lg<<2);
      float4 bv = *(const float4*)&bias[col];
      int row = mBase + mq*64 + i*16 + lr;
      float4* op = (float4*)&out[(size_t)row*192 + col];
      float4 o = *op;
      o.x += bv.x + acc[i][cf][0];
      o.y += bv.y + acc[i][cf][1];
      o.z += bv.z + acc[i][cf][2];
      o.w += bv.w + acc[i][cf][3];
      *op = o;
    }
}

extern "C" void kernel_launch(void* const* d_in, const int* in_sizes, int n_in,
                              void* d_out, int out_size, void* d_ws, size_t ws_size,
                              hipStream_t stream){
  const float* x      = (const float*)d_in[0];
  const float* n1g    = (const float*)d_in[1];
  const float* n1b    = (const float*)d_in[2];
  const float* qkv_w  = (const float*)d_in[3];
  const float* qkv_b  = (const float*)d_in[4];
  const float* proj_w = (const float*)d_in[5];
  const float* proj_b = (const float*)d_in[6];
  const float* rpb    = (const float*)d_in[7];
  const float* n2g    = (const float*)d_in[8];
  const float* n2b    = (const float*)d_in[9];
  const float* fc1_w  = (const float*)d_in[10];
  const float* fc1_b  = (const float*)d_in[11];
  const float* fc2_w  = (const float*)d_in[12];
  const float* fc2_b  = (const float*)d_in[13];
  float* out = (float*)d_out;

  const size_t T = 131072;
  u16* A2     = (u16*)d_ws;            // T*192 bf16
  u16* H1     = A2 + T*192;            // T*768 bf16
  u16* qkvWt  = H1 + T*768;
  u16* projWt = qkvWt + 576*192;
  u16* fc1Wt  = projWt + 192*192;
  u16* fc2Wt  = fc1Wt + 768*192;

  transcast_kernel<<<dim3((192*576+255)/256),256,0,stream>>>(qkv_w, qkvWt, 192, 576);
  transcast_kernel<<<dim3((192*192+255)/256),256,0,stream>>>(proj_w, projWt, 192, 192);
  transcast_kernel<<<dim3((192*768+255)/256),256,0,stream>>>(fc1_w, fc1Wt, 192, 768);
  transcast_kernel<<<dim3((768*192+255)/256),256,0,stream>>>(fc2_w, fc2Wt, 768, 192);

  // LN1 + qkv + attention + proj + residual -> out (xmid)
  attn_fused_kernel<<<dim3(2048),768,0,stream>>>(x, n1g, n1b, qkvWt, qkv_b,
                                                 projWt, proj_b, out, rpb);
  // LN2 -> A2 (bf16)
  ln2_kernel<<<dim3(2048),256,0,stream>>>(out, n2g, n2b, A2);
  // fc1 + GELU -> H1
  fc1_kernel<<<dim3(512),256,0,stream>>>(A2, fc1Wt, fc1_b, H1);
  // fc2 + residual (RMW on out)
  fc2_kernel<<<dim3(512),512,0,stream>>>(H1, fc2Wt, fc2_b, out);
}

// Round 8
// 408.956 us; speedup vs baseline: 1.6099x; 1.2029x over previous
//
#include <hip/hip_runtime.h>
#include <hip/hip_bf16.h>

// Swin block, MI355X. v8: v_cvt_pk_bf16_f32 packing, sigmoid-GELU, fc1 rebuilt
// (32-token waves, no VGPR spill). attn/ln2/fc2 structure kept from v7.
// B=32 H=W=64 C=192 WS=8 SS=4 NH=6 Dh=32; T=131072.

#define DI __device__ __forceinline__

typedef __attribute__((ext_vector_type(8))) short bhalf8;   // 8 bf16 (4 VGPR)
typedef __attribute__((ext_vector_type(4))) float f32x4;
typedef unsigned short u16;
typedef unsigned int   u32;

DI u32 f2bf2(float a, float b){                // pack 2 f32 -> 2 bf16 (1 VALU op)
  u32 r;
  asm("v_cvt_pk_bf16_f32 %0, %1, %2" : "=v"(r) : "v"(a), "v"(b));
  return r;
}
DI u16 f2bf(float f){ return (u16)f2bf2(f, f); }

// gelu ~= x * sigmoid(1.702 x): 5 VALU ops, |err| <= ~0.02 (rare |x|>1.5)
DI float fast_gelu(float x){
  float s = __expf(-1.702f * x);
  return x * __builtin_amdgcn_rcpf(1.0f + s);
}

// window-token index t -> global token g (shift+partition map; gather & scatter identical)
DI int tok2glob(int t){
  int n = t & 63, widx = t >> 6;
  int b = widx >> 6, wi = widx & 63;
  int hh = ((wi >> 3) << 3) + (n >> 3);
  int ww = ((wi & 7) << 3) + (n & 7);
  int hs = (hh + 4) & 63, wsv = (ww + 4) & 63;
  return (b << 12) + (hs << 6) + wsv;
}

DI int region_id(int hpos, int wpos){
  int rh = (hpos < 56) ? 0 : ((hpos < 60) ? 1 : 2);
  int rw = (wpos < 56) ? 0 : ((wpos < 60) ? 1 : 2);
  return rh*3 + rw;
}

// ------------- weight prep: W(K,N) fp32 -> Wt(N,K) bf16 -------------
__global__ void transcast_kernel(const float* __restrict__ W, u16* __restrict__ Wt, int K, int N){
  int idx = blockIdx.x * 256 + threadIdx.x;
  if (idx < K*N){
    int n = idx / K, k = idx - n*K;
    Wt[idx] = f2bf(W[(size_t)k * N + n]);
  }
}

// =================== attn_fused: 1 block / window, 768 threads (12 waves) ===================
__global__ __launch_bounds__(768, 3) void attn_fused_kernel(
    const float* __restrict__ x, const float* __restrict__ n1g, const float* __restrict__ n1b,
    const u16* __restrict__ qkvWt, const float* __restrict__ qkv_b,
    const u16* __restrict__ projWt, const float* __restrict__ proj_b,
    float* __restrict__ out, const float* __restrict__ rpb){
  __shared__ u16 AsB[64*192];      // 24 KB: LN'd tokens; later aliased as Clds
  __shared__ u16 QKB[64*384];      // 48 KB: Q|K tiles; later aliased as P (6 x 64x64)
  __shared__ u16 Vt[6][32*64];     // 24 KB: V^T per head, XOR-swizzled
  __shared__ float Rlds[225*6];
  int widx = blockIdx.x;
  int tid  = threadIdx.x;
  int w = tid >> 6, lane = tid & 63, lr = lane & 15, lg = lane >> 4;

  if (w >= 8){                     // waves 8-11: stage rel-pos bias
    for (int i = tid - 512; i < 225*6; i += 256) Rlds[i] = rpb[i];
  } else {                         // waves 0-7: LN1, 8 threads/row
    int qrow = tid >> 3, oct = tid & 7;
    int g = tok2glob(widx*64 + qrow);
    const float4* xr = (const float4*)(x + (size_t)g*192 + oct*24);
    float4 va[6];
    float s = 0.f, sq = 0.f;
    #pragma unroll
    for (int j = 0; j < 6; j++){
      va[j] = xr[j];
      s  += va[j].x + va[j].y + va[j].z + va[j].w;
      sq += va[j].x*va[j].x + va[j].y*va[j].y + va[j].z*va[j].z + va[j].w*va[j].w;
    }
    s  += __shfl_xor(s, 1, 64);  sq += __shfl_xor(sq, 1, 64);
    s  += __shfl_xor(s, 2, 64);  sq += __shfl_xor(sq, 2, 64);
    s  += __shfl_xor(s, 4, 64);  sq += __shfl_xor(sq, 4, 64);
    float mean = s * (1.f/192.f);
    float rstd = rsqrtf(sq * (1.f/192.f) - mean*mean + 1e-5f);
    const float4* g4 = (const float4*)(n1g + oct*24);
    const float4* b4 = (const float4*)(n1b + oct*24);
    #pragma unroll
    for (int j2 = 0; j2 < 3; j2++){
      float4 v0 = va[2*j2], v1 = va[2*j2+1];
      float4 g0 = g4[2*j2], g1 = g4[2*j2+1];
      float4 b0 = b4[2*j2], b1 = b4[2*j2+1];
      uint4 pk;
      pk.x = f2bf2((v0.x-mean)*rstd*g0.x+b0.x, (v0.y-mean)*rstd*g0.y+b0.y);
      pk.y = f2bf2((v0.z-mean)*rstd*g0.z+b0.z, (v0.w-mean)*rstd*g0.w+b0.w);
      pk.z = f2bf2((v1.x-mean)*rstd*g1.x+b1.x, (v1.y-mean)*rstd*g1.y+b1.y);
      pk.w = f2bf2((v1.z-mean)*rstd*g1.z+b1.z, (v1.w-mean)*rstd*g1.w+b1.w);
      int gk = oct*3 + j2;
      *(uint4*)&AsB[qrow*192 + ((gk ^ (qrow & 7)) << 3)] = pk;
    }
  }
  __syncthreads();                 // AsB + Rlds ready

  // ---- qkv GEMM: wave w computes output cols [w*48, w*48+48) ----
  #pragma unroll
  for (int nf = 0; nf < 3; nf++){
    int cBase = w*48 + nf*16;
    bhalf8 wF[6];
    #pragma unroll
    for (int kk = 0; kk < 6; kk++)
      wF[kk] = *(const bhalf8*)&qkvWt[(size_t)(cBase + lr)*192 + kk*32 + (lg<<3)];
    float4 bv = *(const float4*)&qkv_b[cBase + (lg<<2)];
    #pragma unroll
    for (int i = 0; i < 4; i++){
      f32x4 a0 = (f32x4){0.f,0.f,0.f,0.f}, a1 = (f32x4){0.f,0.f,0.f,0.f};
      #pragma unroll
      for (int kk = 0; kk < 3; kk++){
        int row = i*16 + lr;
        bhalf8 t0 = *(const bhalf8*)&AsB[row*192 + (((2*kk*4     + lg) ^ (row & 7)) << 3)];
        bhalf8 t1 = *(const bhalf8*)&AsB[row*192 + ((((2*kk+1)*4 + lg) ^ (row & 7)) << 3)];
        a0 = __builtin_amdgcn_mfma_f32_16x16x32_bf16(wF[2*kk],   t0, a0, 0, 0, 0);
        a1 = __builtin_amdgcn_mfma_f32_16x16x32_bf16(wF[2*kk+1], t1, a1, 0, 0, 0);
      }
      float v0 = a0[0]+a1[0]+bv.x, v1 = a0[1]+a1[1]+bv.y;
      float v2 = a0[2]+a1[2]+bv.z, v3 = a0[3]+a1[3]+bv.w;
      int token = i*16 + lr;
      if (cBase < 384){            // Q|K: packed uint2 into swizzled QKB
        int gq = (cBase >> 3) + (lg >> 1);
        uint2 pk; pk.x = f2bf2(v0, v1); pk.y = f2bf2(v2, v3);
        *(uint2*)&QKB[token*384 + ((gq ^ (token & 7)) << 3) + ((lg & 1) << 2)] = pk;
      } else {                     // V: transposed scatter into Vt
        int d0 = cBase + (lg<<2) - 384;
        int hv = d0 >> 5;
        int db = d0 & 31;
        Vt[hv][(db+0)*64 + (token ^ (((db+0)&7)<<3))] = f2bf(v0);
        Vt[hv][(db+1)*64 + (token ^ (((db+1)&7)<<3))] = f2bf(v1);
        Vt[hv][(db+2)*64 + (token ^ (((db+2)&7)<<3))] = f2bf(v2);
        Vt[hv][(db+3)*64 + (token ^ (((db+3)&7)<<3))] = f2bf(v3);
      }
    }
  }
  __syncthreads();                 // QKB + Vt complete

  // ---- scores: wave (hd, half) = head hd, q-rows [half*32, half*32+32) ----
  int hd   = (w < 6) ? w : (w - 6);
  int half = (w < 6) ? 0 : 1;
  bhalf8 qf[2], kf[4];
  #pragma unroll
  for (int i = 0; i < 2; i++){
    int token = (half*2 + i)*16 + lr;
    int gq = hd*4 + lg;
    qf[i] = *(const bhalf8*)&QKB[token*384 + ((gq ^ (token & 7)) << 3)];
  }
  #pragma unroll
  for (int j = 0; j < 4; j++){
    int token = j*16 + lr;
    int gk = 24 + hd*4 + lg;
    kf[j] = *(const bhalf8*)&QKB[token*384 + ((gk ^ (token & 7)) << 3)];
  }
  f32x4 sc[2][4];
  f32x4 zero = (f32x4){0.f,0.f,0.f,0.f};
  #pragma unroll
  for (int i = 0; i < 2; i++)
    #pragma unroll
    for (int j = 0; j < 4; j++)
      sc[i][j] = __builtin_amdgcn_mfma_f32_16x16x32_bf16(qf[i], kf[j], zero, 0, 0, 0);
  __syncthreads();                 // all QKB reads done -> safe to overwrite with P

  // ---- softmax (+rel-pos bias +shift mask), P into QKB region ----
  u16* Plds = &QKB[0];
  int mwin = widx >> 5;            // faithful to reference reshape quirk
  int mh0 = (mwin >> 3) << 3, mw0 = (mwin & 7) << 3;
  #pragma unroll
  for (int i = 0; i < 2; i++){
    #pragma unroll
    for (int r = 0; r < 4; r++){
      int row = (half*2 + i)*16 + lg*4 + r;
      int ih = row >> 3, iw = row & 7;
      int ridr = region_id(mh0 + ih, mw0 + iw);
      float vals[4];
      #pragma unroll
      for (int j = 0; j < 4; j++){
        int col = j*16 + lr;
        int jh = col >> 3, jw = col & 7;
        float bias = Rlds[((ih-jh+7)*15 + (iw-jw+7))*6 + hd];
        int ridc = region_id(mh0 + jh, mw0 + jw);
        vals[j] = sc[i][j][r] * 0.17677669529663687f + bias + ((ridr==ridc) ? 0.f : -100.f);
      }
      float mx = fmaxf(fmaxf(vals[0],vals[1]), fmaxf(vals[2],vals[3]));
      #pragma unroll
      for (int d = 1; d < 16; d <<= 1) mx = fmaxf(mx, __shfl_xor(mx, d, 64));
      float sum = 0.f;
      #pragma unroll
      for (int j = 0; j < 4; j++){ vals[j] = __expf(vals[j]-mx); sum += vals[j]; }
      #pragma unroll
      for (int d = 1; d < 16; d <<= 1) sum += __shfl_xor(sum, d, 64);
      float inv = __builtin_amdgcn_rcpf(sum);
      #pragma unroll
      for (int j = 0; j < 4; j++){
        int col = j*16 + lr;
        Plds[hd*4096 + row*64 + (col ^ ((row & 7) << 3))] = f2bf(vals[j]*inv);
      }
    }
  }

  // ---- PV: wave-local P rows + Vt[hd] ----
  f32x4 oa[2][2];
  #pragma unroll
  for (int i=0;i<2;i++)
    #pragma unroll
    for (int n=0;n<2;n++) oa[i][n] = zero;
  #pragma unroll
  for (int kb = 0; kb < 2; kb++){
    bhalf8 pf[2], vf[2];
    int k = (kb<<5) + (lg<<3);
    #pragma unroll
    for (int i = 0; i < 2; i++){
      int row = (half*2 + i)*16 + lr;
      pf[i] = *(const bhalf8*)&Plds[hd*4096 + row*64 + (k ^ ((row&7)<<3))];
    }
    #pragma unroll
    for (int n = 0; n < 2; n++){
      int d = n*16 + lr;
      vf[n] = *(const bhalf8*)&Vt[hd][d*64 + (k ^ ((d&7)<<3))];
    }
    #pragma unroll
    for (int i=0;i<2;i++)
      #pragma unroll
      for (int n=0;n<2;n++)
        oa[i][n] = __builtin_amdgcn_mfma_f32_16x16x32_bf16(pf[i], vf[n], oa[i][n], 0, 0, 0);
  }

  // ---- ctx -> Clds (aliases AsB; AsB dead since qkv barrier) ----
  u16* Clds = &AsB[0];
  #pragma unroll
  for (int i=0;i<2;i++)
    #pragma unroll
    for (int n=0;n<2;n++)
      #pragma unroll
      for (int r=0;r<4;r++){
        int row = (half*2 + i)*16 + lg*4 + r;
        int col = hd*32 + n*16 + lr;
        Clds[row*192 + (((col>>3) ^ (row&7)) << 3) + (col & 7)] = f2bf(oa[i][n][r]);
      }
  __syncthreads();                 // ctx complete

  // ---- proj + residual scatter; wave does rows [half*32,+32), cols [hd*32,+32) ----
  f32x4 pacc[2][2];
  #pragma unroll
  for (int i=0;i<2;i++)
    #pragma unroll
    for (int n=0;n<2;n++) pacc[i][n] = zero;
  #pragma unroll
  for (int kk = 0; kk < 6; kk++){
    bhalf8 af[2], bf[2];
    #pragma unroll
    for (int i = 0; i < 2; i++){
      int row = half*32 + i*16 + lr;
      af[i] = *(const bhalf8*)&Clds[row*192 + (((kk*4 + lg) ^ (row & 7)) << 3)];
    }
    #pragma unroll
    for (int n = 0; n < 2; n++){
      int col = hd*32 + n*16 + lr;
      bf[n] = *(const bhalf8*)&projWt[(size_t)col*192 + kk*32 + (lg<<3)];
    }
    #pragma unroll
    for (int i=0;i<2;i++)
      #pragma unroll
      for (int n=0;n<2;n++)
        pacc[i][n] = __builtin_amdgcn_mfma_f32_16x16x32_bf16(af[i], bf[n], pacc[i][n], 0, 0, 0);
  }
  #pragma unroll
  for (int i=0;i<2;i++)
    #pragma unroll
    for (int n=0;n<2;n++){
      int col = hd*32 + n*16 + lr;
      float bv = proj_b[col];
      #pragma unroll
      for (int r=0;r<4;r++){
        int rowl = half*32 + i*16 + lg*4 + r;
        int g = tok2glob(widx*64 + rowl);
        size_t o = (size_t)g*192 + col;
        out[o] = x[o] + bv + pacc[i][n][r];
      }
    }
}

// =================== ln2: out(fp32) -> A2(bf16), 64 rows/block ===================
__global__ __launch_bounds__(256) void ln2_kernel(const float* __restrict__ X,
    const float* __restrict__ gam, const float* __restrict__ bet, u16* __restrict__ A2){
  int tid = threadIdx.x;
  int row = (blockIdx.x << 6) + (tid >> 2), quarter = tid & 3;
  const float4* xr = (const float4*)(X + (size_t)row*192 + quarter*48);
  float4 va[12];
  float s = 0.f, sq = 0.f;
  #pragma unroll
  for (int j = 0; j < 12; j++){
    va[j] = xr[j];
    s  += va[j].x + va[j].y + va[j].z + va[j].w;
    sq += va[j].x*va[j].x + va[j].y*va[j].y + va[j].z*va[j].z + va[j].w*va[j].w;
  }
  s  += __shfl_xor(s, 1, 64);  sq += __shfl_xor(sq, 1, 64);
  s  += __shfl_xor(s, 2, 64);  sq += __shfl_xor(sq, 2, 64);
  float mean = s * (1.f/192.f);
  float rstd = rsqrtf(sq * (1.f/192.f) - mean*mean + 1e-5f);
  const float4* g4 = (const float4*)(gam + quarter*48);
  const float4* b4 = (const float4*)(bet + quarter*48);
  #pragma unroll
  for (int j2 = 0; j2 < 6; j2++){
    float4 v0 = va[2*j2], v1 = va[2*j2+1];
    float4 g0 = g4[2*j2], g1 = g4[2*j2+1];
    float4 b0 = b4[2*j2], b1 = b4[2*j2+1];
    uint4 pk;
    pk.x = f2bf2((v0.x-mean)*rstd*g0.x+b0.x, (v0.y-mean)*rstd*g0.y+b0.y);
    pk.y = f2bf2((v0.z-mean)*rstd*g0.z+b0.z, (v0.w-mean)*rstd*g0.w+b0.w);
    pk.z = f2bf2((v1.x-mean)*rstd*g1.x+b1.x, (v1.y-mean)*rstd*g1.y+b1.y);
    pk.w = f2bf2((v1.z-mean)*rstd*g1.z+b1.z, (v1.w-mean)*rstd*g1.w+b1.w);
    *(uint4*)&A2[(size_t)row*192 + quarter*48 + j2*8] = pk;
  }
}

// =================== fc1: 256 tokens/block, 8 waves x 32 tokens, W LDS-dbuf ===================
__global__ __launch_bounds__(512, 4) void fc1_kernel(const u16* __restrict__ A2,
    const u16* __restrict__ Bt, const float* __restrict__ bias, u16* __restrict__ H1){
  __shared__ u16 Wl[2][64*192];               // 24 KB each, granule-swizzled
  int tid = threadIdx.x;
  int mBase = blockIdx.x << 8;                // 256 tokens
  int lane = tid & 63, w = tid >> 6;
  int lr = lane & 15, lg = lane >> 4;
  int tokBase = mBase + (w << 5);             // wave's 32 tokens

  // hoist A fragments: 32 tokens x K=192 in regs (12 bhalf8 = 48 VGPR)
  bhalf8 tF[2][6];
  #pragma unroll
  for (int i = 0; i < 2; i++)
    #pragma unroll
    for (int kk = 0; kk < 6; kk++)
      tF[i][kk] = *(const bhalf8*)&A2[(size_t)(tokBase + i*16 + lr)*192 + kk*32 + (lg<<3)];

  // stage: thread t -> col = t>>3, granules (t&7)*3 + j
  int scol = tid >> 3, sg0 = (tid & 7) * 3;
  #define STAGE_FC1(nt, buf) { \
    const u16* sp = Bt + (size_t)((nt)*64 + scol)*192 + sg0*8; \
    _Pragma("unroll") \
    for (int j = 0; j < 3; j++){ \
      uint4 v = *(const uint4*)(sp + j*8); \
      *(uint4*)&Wl[buf][scol*192 + (((sg0 + j) ^ (scol & 7)) << 3)] = v; \
    } }

  STAGE_FC1(0, 0)
  for (int nt = 0; nt < 12; nt++){
    __syncthreads();
    if (nt < 11) STAGE_FC1(nt + 1, (nt + 1) & 1)
    int buf = nt & 1;
    #pragma unroll
    for (int cf = 0; cf < 4; cf++){
      bhalf8 wF[6];
      int col = cf*16 + lr;
      #pragma unroll
      for (int kk = 0; kk < 6; kk++)
        wF[kk] = *(const bhalf8*)&Wl[buf][col*192 + (((kk*4 + lg) ^ (col & 7)) << 3)];
      int gcol = (nt << 6) + cf*16;
      float4 bv = *(const float4*)&bias[gcol + (lg<<2)];
      #pragma unroll
      for (int i = 0; i < 2; i++){
        f32x4 a0 = (f32x4){0.f,0.f,0.f,0.f}, a1 = (f32x4){0.f,0.f,0.f,0.f};
        #pragma unroll
        for (int kk = 0; kk < 3; kk++){
          a0 = __builtin_amdgcn_mfma_f32_16x16x32_bf16(wF[2*kk],   tF[i][2*kk],   a0, 0, 0, 0);
          a1 = __builtin_amdgcn_mfma_f32_16x16x32_bf16(wF[2*kk+1], tF[i][2*kk+1], a1, 0, 0, 0);
        }
        float v0 = fast_gelu(a0[0]+a1[0]+bv.x);
        float v1 = fast_gelu(a0[1]+a1[1]+bv.y);
        float v2 = fast_gelu(a0[2]+a1[2]+bv.z);
        float v3 = fast_gelu(a0[3]+a1[3]+bv.w);
        uint2 pk; pk.x = f2bf2(v0, v1); pk.y = f2bf2(v2, v3);
        *(uint2*)&H1[(size_t)(tokBase + i*16 + lr)*768 + gcol + (lg<<2)] = pk;
      }
    }
  }
  #undef STAGE_FC1
}

// =================== fc2: 256 tokens/block, 8 waves, H+W LDS-dbuf, residual RMW ===================
__global__ __launch_bounds__(512, 2) void fc2_kernel(const u16* __restrict__ H1,
    const u16* __restrict__ Bt, const float* __restrict__ bias, float* out){
  __shared__ u16 Hl[2][256*64];               // 32 KB each
  __shared__ u16 Wl[2][192*64];               // 24 KB each
  int tid = threadIdx.x;
  int mBase = blockIdx.x << 8;                // 256 tokens
  int lane = tid & 63, w = tid >> 6;
  int lr = lane & 15, lg = lane >> 4;
  int mq = w >> 1, nh = w & 1;                // wave = 64 tokens x 96 cols

  int srow = tid >> 3, sgk = tid & 7;
  #define STAGE_FC2(p, buf) { \
    _Pragma("unroll") \
    for (int j = 0; j < 4; j++){ \
      int tok = j*64 + srow; \
      uint4 v = *(const uint4*)&H1[(size_t)(mBase + tok)*768 + (p)*64 + sgk*8]; \
      *(uint4*)&Hl[buf][tok*64 + ((sgk ^ (tok & 7)) << 3)] = v; \
    } \
    _Pragma("unroll") \
    for (int j = 0; j < 3; j++){ \
      int col = j*64 + srow; \
      uint4 v = *(const uint4*)&Bt[(size_t)col*768 + (p)*64 + sgk*8]; \
      *(uint4*)&Wl[buf][col*64 + ((sgk ^ (col & 7)) << 3)] = v; \
    } }

  f32x4 acc[4][6];
  #pragma unroll
  for (int i = 0; i < 4; i++)
    #pragma unroll
    for (int cf = 0; cf < 6; cf++) acc[i][cf] = (f32x4){0.f,0.f,0.f,0.f};

  STAGE_FC2(0, 0)
  for (int p = 0; p < 12; p++){
    __syncthreads();
    if (p < 11) STAGE_FC2(p + 1, (p + 1) & 1)
    int buf = p & 1;
    #pragma unroll
    for (int kk = 0; kk < 2; kk++){
      bhalf8 hF[4], wv[6];
      #pragma unroll
      for (int i = 0; i < 4; i++){
        int tok = mq*64 + i*16 + lr;
        hF[i] = *(const bhalf8*)&Hl[buf][tok*64 + (((kk*4 + lg) ^ (tok & 7)) << 3)];
      }
      #pragma unroll
      for (int cf = 0; cf < 6; cf++){
        int col = nh*96 + cf*16 + lr;
        wv[cf] = *(const bhalf8*)&Wl[buf][col*64 + (((kk*4 + lg) ^ (col & 7)) << 3)];
      }
      #pragma unroll
      for (int i = 0; i < 4; i++)
        #pragma unroll
        for (int cf = 0; cf < 6; cf++)
          acc[i][cf] = __builtin_amdgcn_mfma_f32_16x16x32_bf16(wv[cf], hF[i], acc[i][cf], 0, 0, 0);
    }
  }
  #undef STAGE_FC2

  #pragma unroll
  for (int i = 0; i < 4; i++)
    #pragma unroll
    for (int cf = 0; cf < 6; cf++){
      int col = nh*96 + cf*16 + (lg<<2);
      float4 bv = *(const float4*)&bias[col];
      int row = mBase + mq*64 + i*16 + lr;
      float4* op = (float4*)&out[(size_t)row*192 + col];
      float4 o = *op;
      o.x += bv.x + acc[i][cf][0];
      o.y += bv.y + acc[i][cf][1];
      o.z += bv.z + acc[i][cf][2];
      o.w += bv.w + acc[i][cf][3];
      *op = o;
    }
}

extern "C" void kernel_launch(void* const* d_in, const int* in_sizes, int n_in,
                              void* d_out, int out_size, void* d_ws, size_t ws_size,
                              hipStream_t stream){
  const float* x      = (const float*)d_in[0];
  const float* n1g    = (const float*)d_in[1];
  const float* n1b    = (const float*)d_in[2];
  const float* qkv_w  = (const float*)d_in[3];
  const float* qkv_b  = (const float*)d_in[4];
  const float* proj_w = (const float*)d_in[5];
  const float* proj_b = (const float*)d_in[6];
  const float* rpb    = (const float*)d_in[7];
  const float* n2g    = (const float*)d_in[8];
  const float* n2b    = (const float*)d_in[9];
  const float* fc1_w  = (const float*)d_in[10];
  const float* fc1_b  = (const float*)d_in[11];
  const float* fc2_w  = (const float*)d_in[12];
  const float* fc2_b  = (const float*)d_in[13];
  float* out = (float*)d_out;

  const size_t T = 131072;
  u16* A2     = (u16*)d_ws;            // T*192 bf16
  u16* H1     = A2 + T*192;            // T*768 bf16
  u16* qkvWt  = H1 + T*768;
  u16* projWt = qkvWt + 576*192;
  u16* fc1Wt  = projWt + 192*192;
  u16* fc2Wt  = fc1Wt + 768*192;

  transcast_kernel<<<dim3((192*576+255)/256),256,0,stream>>>(qkv_w, qkvWt, 192, 576);
  transcast_kernel<<<dim3((192*192+255)/256),256,0,stream>>>(proj_w, projWt, 192, 192);
  transcast_kernel<<<dim3((192*768+255)/256),256,0,stream>>>(fc1_w, fc1Wt, 192, 768);
  transcast_kernel<<<dim3((768*192+255)/256),256,0,stream>>>(fc2_w, fc2Wt, 768, 192);

  // LN1 + qkv + attention + proj + residual -> out (xmid)
  attn_fused_kernel<<<dim3(2048),768,0,stream>>>(x, n1g, n1b, qkvWt, qkv_b,
                                                 projWt, proj_b, out, rpb);
  // LN2 -> A2 (bf16)
  ln2_kernel<<<dim3(2048),256,0,stream>>>(out, n2g, n2b, A2);
  // fc1 + GELU -> H1
  fc1_kernel<<<dim3(512),512,0,stream>>>(A2, fc1Wt, fc1_b, H1);
  // fc2 + residual (RMW on out)
  fc2_kernel<<<dim3(512),512,0,stream>>>(H1, fc2Wt, fc2_b, out);
}